// Round 4
// baseline (319.433 us; speedup 1.0000x reference)
//
#include <hip/hip_runtime.h>

// ---------------- constants ----------------
#define BATCH   131072
#define INDIM   1024
#define BM      64
#define BDIM    256
#define NBLK    (BATCH / BM)          // 2048

// ---- LDS layout (bytes), phase-multiplexed ----
#define WT0_OFF  0                    // GEMM1 w-tile buf0 [384][32] bf16 (24576)
#define WT1_OFF  24576                // buf1 -> ends 49152
#define XT0_OFF  49152                // GEMM1 x-tile buf0 [64][32] (4096)
#define XT1_OFF  53248                // buf1 -> ends 57344
#define Z1_OFF   0                    // z1 [64][392] bf16 (50176)
#define W2T_OFF  57344                // GEMM2 w-tile [128][32] (8192) -> 65536
#define FZ_OFF   0                    // fused [64][264] bf16 (33792)
#define LG_OFF   33792                // logits [64][33] f32 (8448) -> 42240
#define W3T_OFF  42240                // GEMM3 w-tile [384][32] (24576) -> 66816
#define RP_OFF   0                    // rowpart [64][4] f32 (aliases fz)
#define CB_OFF   66816
#define B1S_OFF  (CB_OFF)             // 384 f32
#define B2S_OFF  (CB_OFF + 1536)     // 128 f32
#define B3S_OFF  (CB_OFF + 2048)     // 384 f32
#define W4S_OFF  (CB_OFF + 3584)     // 384 f32
#define MKS_OFF  (CB_OFF + 5120)     // mk bf16 [32][136] (8704)
#define SMEM_BYTES (CB_OFF + 13824)  // 80640 -> 2 blocks/CU

typedef unsigned short u16;
typedef u16    u16x8  __attribute__((ext_vector_type(8)));
typedef __bf16 bf16x8 __attribute__((ext_vector_type(8)));
typedef float  f32x4  __attribute__((ext_vector_type(4)));

__device__ __forceinline__ u16 f2bf(float f) {
  unsigned u = __float_as_uint(f);
  u += 0x7FFFu + ((u >> 16) & 1u);    // RNE
  return (u16)(u >> 16);
}

__device__ __forceinline__ float gelu_exact(float v) {
  return 0.5f * v * (1.0f + erff(v * 0.70710678118654752440f));
}

__device__ __forceinline__ f32x4 mfma16(u16x8 a, u16x8 b, f32x4 c) {
  return __builtin_amdgcn_mfma_f32_16x16x32_bf16(
      __builtin_bit_cast(bf16x8, a), __builtin_bit_cast(bf16x8, b), c, 0, 0, 0);
}

__device__ __forceinline__ u16x8 cvt8(float4 a, float4 b) {
  bf16x8 r;
  r[0]=(__bf16)a.x; r[1]=(__bf16)a.y; r[2]=(__bf16)a.z; r[3]=(__bf16)a.w;
  r[4]=(__bf16)b.x; r[5]=(__bf16)b.y; r[6]=(__bf16)b.z; r[7]=(__bf16)b.w;
  return __builtin_bit_cast(u16x8, r);
}

typedef __attribute__((address_space(3))) unsigned int       lds_u32;
typedef __attribute__((address_space(1))) const unsigned int glb_u32;
__device__ __forceinline__ void gload16(const void* g, void* l) {
  __builtin_amdgcn_global_load_lds((glb_u32*)g, (lds_u32*)l, 16, 0, 0);
}

#define WAIT_VM0 do { \
  asm volatile("s_waitcnt vmcnt(0)" ::: "memory"); \
  __builtin_amdgcn_sched_barrier(0); } while (0)
#define WAIT_LGKM0 asm volatile("s_waitcnt lgkmcnt(0)" ::: "memory")

// ---------------- prep: bf16-cast + transpose into plain [N][32] K-tiles ----------------
__global__ void prep_kernel(const float* __restrict__ w1, const float* __restrict__ w2,
                            const float* __restrict__ w3, u16* __restrict__ w1s,
                            u16* __restrict__ w2s, u16* __restrict__ w3s) {
  int i = blockIdx.x * 256 + threadIdx.x;
  if (i < 393216) {                       // 32 tiles [384][32]
    int t = i / 12288, p = i % 12288;
    int r = p >> 5, c = p & 31;
    w1s[i] = f2bf(w1[(t * 32 + c) * 384 + r]);
  } else if (i < 442368) {                // 12 tiles [128][32]
    int j = i - 393216;
    int t = j / 4096, p = j % 4096;
    int r = p >> 5, c = p & 31;
    w2s[j] = f2bf(w2[(t * 32 + c) * 128 + r]);
  } else if (i < 540672) {                // 8 tiles [384][32]
    int j = i - 442368;
    int t = j / 12288, p = j % 12288;
    int r = p >> 5, c = p & 31;
    w3s[j] = f2bf(w3[(t * 32 + c) * 384 + r]);
  }
}

// ---------------- fused forward ----------------
__global__ __launch_bounds__(BDIM, 2) void fused_kernel(
    const float* __restrict__ x,  const u16* __restrict__ w1s,
    const float* __restrict__ b1, const u16* __restrict__ w2s,
    const float* __restrict__ b2, const float* __restrict__ mkw,
    const float* __restrict__ mvw, const u16* __restrict__ w3s,
    const float* __restrict__ b3, const float* __restrict__ w4,
    const float* __restrict__ b4, float* __restrict__ out) {
  extern __shared__ char smem[];
  u16*   z1  = (u16*)(smem + Z1_OFF);
  u16*   w2t = (u16*)(smem + W2T_OFF);
  u16*   fz  = (u16*)(smem + FZ_OFF);
  float* lgs = (float*)(smem + LG_OFF);
  u16*   w3t = (u16*)(smem + W3T_OFF);
  float* b1s = (float*)(smem + B1S_OFF);
  float* b2s = (float*)(smem + B2S_OFF);
  float* b3s = (float*)(smem + B3S_OFF);
  float* w4s = (float*)(smem + W4S_OFF);
  u16*   mks = (u16*)(smem + MKS_OFF);
  float* rowpart = (float*)(smem + RP_OFF);

  const int tid  = threadIdx.x;
  const int lane = tid & 63;
  const int wid  = tid >> 6;          // 0..3 == waveN
  const int l15  = lane & 15;
  const int g    = lane >> 4;         // 0..3 (K chunk)
  const int row0 = blockIdx.x * BM;

  const int sr = tid >> 2;            // 0..63 (x row)
  const int sj = tid & 3;             // x col-octet

  // ---------- prologue ----------
  // tile-0 w DMA
  {
    const u16* ws = w1s + wid * 3072 + lane * 8;
    u16* wd = (u16*)(smem + WT0_OFF) + wid * 3072;
    #pragma unroll
    for (int i = 0; i < 6; ++i) gload16(ws + i * 512, wd + i * 512);
  }
  // x(0) loads
  const float* xq = x + (long)(row0 + sr) * INDIM + sj * 8;
  float4 xr0 = *(const float4*)xq, xr1 = *(const float4*)(xq + 4);

  // constants (cover DMA flight)
  for (int i = tid; i < 384; i += BDIM) b1s[i] = b1[i];
  for (int i = tid; i < 128; i += BDIM) b2s[i] = b2[i];
  for (int i = tid; i < 384; i += BDIM) b3s[i] = b3[i];
  for (int i = tid; i < 384; i += BDIM) w4s[i] = w4[i];
  {
    int r = tid >> 3, cc = (tid & 7) * 16;
    const float4* p = (const float4*)(mkw + r * 128 + cc);
    float4 a = p[0], b = p[1], c = p[2], d = p[3];
    *(u16x8*)(mks + r * 136 + cc)     = cvt8(a, b);
    *(u16x8*)(mks + r * 136 + cc + 8) = cvt8(c, d);
  }
  // publish xt[0] (waits x(0); drains tile-0 DMA too — prologue only)
  *(u16x8*)((u16*)(smem + XT0_OFF) + sr * 32 + sj * 8) = cvt8(xr0, xr1);
  // tile-1 w DMA
  {
    const u16* ws = w1s + 12288 + wid * 3072 + lane * 8;
    u16* wd = (u16*)(smem + WT1_OFF) + wid * 3072;
    #pragma unroll
    for (int i = 0; i < 6; ++i) gload16(ws + i * 512, wd + i * 512);
  }
  // x(1) loads
  { const float* p = xq + 32; xr0 = *(const float4*)p; xr1 = *(const float4*)(p + 4); }
  asm volatile("s_waitcnt vmcnt(8) lgkmcnt(0)" ::: "memory");
  __builtin_amdgcn_s_barrier();
  __builtin_amdgcn_sched_barrier(0);

  // =========== GEMM1: z1 = gelu(x @ w1 + b1)  [64 x 384], K=1024, BK=32 ===========
  f32x4 acc[4][6];
  #pragma unroll
  for (int m = 0; m < 4; ++m)
    #pragma unroll
    for (int n = 0; n < 6; ++n) acc[m][n] = (f32x4){0.f, 0.f, 0.f, 0.f};

  for (int kt = 0; kt < 30; ++kt) {
    const u16* xb = (u16*)(smem + ((kt & 1) ? XT1_OFF : XT0_OFF));
    const u16* wb = (u16*)(smem + ((kt & 1) ? WT1_OFF : WT0_OFF));
    u16x8 af[4], bfr[6];
    #pragma unroll
    for (int m = 0; m < 4; ++m) af[m] = *(const u16x8*)(xb + (m * 16 + l15) * 32 + g * 8);
    #pragma unroll
    for (int n = 0; n < 6; ++n)
      bfr[n] = *(const u16x8*)(wb + (wid * 96 + n * 16 + l15) * 32 + g * 8);
    WAIT_LGKM0;                       // my frag reads done -> my wt quarter reusable
    {   // w-tile DMA (kt+2) into buffer just freed (own quarter only)
      const u16* ws = w1s + (kt + 2) * 12288 + wid * 3072 + lane * 8;
      u16* wd = (u16*)(smem + ((kt & 1) ? WT1_OFF : WT0_OFF)) + wid * 3072;
      #pragma unroll
      for (int i = 0; i < 6; ++i) gload16(ws + i * 512, wd + i * 512);
    }
    __builtin_amdgcn_s_setprio(1);
    #pragma unroll
    for (int m = 0; m < 4; ++m)
      #pragma unroll
      for (int n = 0; n < 6; ++n) acc[m][n] = mfma16(af[m], bfr[n], acc[m][n]);
    __builtin_amdgcn_s_setprio(0);
    {   // publish xt[kt+1]; implicit wait drains only >=1-iter-old loads
      u16* xn = (u16*)(smem + ((kt & 1) ? XT0_OFF : XT1_OFF));
      *(u16x8*)(xn + sr * 32 + sj * 8) = cvt8(xr0, xr1);
    }
    {   // stream x(kt+2)
      const float* p = xq + (kt + 2) * 32;
      xr0 = *(const float4*)p; xr1 = *(const float4*)(p + 4);
    }
    asm volatile("s_waitcnt vmcnt(8) lgkmcnt(0)" ::: "memory");
    __builtin_amdgcn_s_barrier();
    __builtin_amdgcn_sched_barrier(0);
  }
  {   // kt = 30 (no more DMA / x loads)
    const u16* xb = (u16*)(smem + XT0_OFF);
    const u16* wb = (u16*)(smem + WT0_OFF);
    u16x8 af[4], bfr[6];
    #pragma unroll
    for (int m = 0; m < 4; ++m) af[m] = *(const u16x8*)(xb + (m * 16 + l15) * 32 + g * 8);
    #pragma unroll
    for (int n = 0; n < 6; ++n)
      bfr[n] = *(const u16x8*)(wb + (wid * 96 + n * 16 + l15) * 32 + g * 8);
    WAIT_LGKM0;
    __builtin_amdgcn_s_setprio(1);
    #pragma unroll
    for (int m = 0; m < 4; ++m)
      #pragma unroll
      for (int n = 0; n < 6; ++n) acc[m][n] = mfma16(af[m], bfr[n], acc[m][n]);
    __builtin_amdgcn_s_setprio(0);
    {   // publish xt[31] (drains DMA(31) for next reads)
      u16* xn = (u16*)(smem + XT1_OFF);
      *(u16x8*)(xn + sr * 32 + sj * 8) = cvt8(xr0, xr1);
    }
    asm volatile("s_waitcnt vmcnt(0) lgkmcnt(0)" ::: "memory");
    __builtin_amdgcn_s_barrier();
    __builtin_amdgcn_sched_barrier(0);
  }
  {   // kt = 31
    const u16* xb = (u16*)(smem + XT1_OFF);
    const u16* wb = (u16*)(smem + WT1_OFF);
    u16x8 af[4], bfr[6];
    #pragma unroll
    for (int m = 0; m < 4; ++m) af[m] = *(const u16x8*)(xb + (m * 16 + l15) * 32 + g * 8);
    #pragma unroll
    for (int n = 0; n < 6; ++n)
      bfr[n] = *(const u16x8*)(wb + (wid * 96 + n * 16 + l15) * 32 + g * 8);
    WAIT_LGKM0;
    #pragma unroll
    for (int m = 0; m < 4; ++m)
      #pragma unroll
      for (int n = 0; n < 6; ++n) acc[m][n] = mfma16(af[m], bfr[n], acc[m][n]);
  }
  __syncthreads();                    // all staging reads done -> z1 region reusable

  // GEMM2 tile-0 DMA early (covered by z1 epilogue)
  {
    const u16* s2 = w2s + wid * 1024 + lane * 8;
    gload16(s2, w2t + wid * 1024);
    gload16(s2 + 512, w2t + wid * 1024 + 512);
  }
  // z1 epilogue
  #pragma unroll
  for (int m = 0; m < 4; ++m) {
    #pragma unroll
    for (int n = 0; n < 6; ++n) {
      int col = wid * 96 + n * 16 + l15;
      float bias = b1s[col];
      #pragma unroll
      for (int j = 0; j < 4; ++j)
        z1[(m * 16 + g * 4 + j) * 392 + col] = f2bf(gelu_exact(acc[m][n][j] + bias));
    }
  }
  __syncthreads();                    // z1 published

  // =========== GEMM2: z = gelu(z1 @ w2 + b2)  [64 x 128], K=384, BK=32, no barriers ===========
  f32x4 acc2[4][2];
  #pragma unroll
  for (int m = 0; m < 4; ++m) { acc2[m][0] = (f32x4){0,0,0,0}; acc2[m][1] = (f32x4){0,0,0,0}; }
  for (int kt = 0; kt < 12; ++kt) {
    WAIT_VM0;                         // my tile kt landed
    u16x8 a2f[4], b2f[2];
    #pragma unroll
    for (int m = 0; m < 4; ++m)
      a2f[m] = *(const u16x8*)(z1 + (m * 16 + l15) * 392 + kt * 32 + g * 8);
    #pragma unroll
    for (int n = 0; n < 2; ++n)
      b2f[n] = *(const u16x8*)(w2t + (wid * 32 + n * 16 + l15) * 32 + g * 8);
    WAIT_LGKM0;
    if (kt < 11) {
      const u16* s2 = w2s + (kt + 1) * 4096 + wid * 1024 + lane * 8;
      gload16(s2, w2t + wid * 1024);
      gload16(s2 + 512, w2t + wid * 1024 + 512);
    }
    __builtin_amdgcn_s_setprio(1);
    #pragma unroll
    for (int m = 0; m < 4; ++m)
      #pragma unroll
      for (int n = 0; n < 2; ++n) acc2[m][n] = mfma16(a2f[m], b2f[n], acc2[m][n]);
    __builtin_amdgcn_s_setprio(0);
  }
  __syncthreads();                    // z1/w2t reads done -> fz & w3t regions usable

  // GEMM3 tile-0 DMA very early (covered by fz epilogue + logits + top2)
  {
    const u16* s3 = w3s + wid * 3072 + lane * 8;
    u16* d3 = w3t + wid * 3072;
    #pragma unroll
    for (int i = 0; i < 6; ++i) gload16(s3 + i * 512, d3 + i * 512);
  }
  // fz epilogue (z part)
  #pragma unroll
  for (int m = 0; m < 4; ++m) {
    #pragma unroll
    for (int n = 0; n < 2; ++n) {
      int col = wid * 32 + n * 16 + l15;
      float bias = b2s[col];
      #pragma unroll
      for (int j = 0; j < 4; ++j)
        fz[(m * 16 + g * 4 + j) * 264 + col] = f2bf(gelu_exact(acc2[m][n][j] + bias));
    }
  }
  __syncthreads();                    // fz(z) published

  // =========== logits = (z @ mk^T)/tau  [64 x 32]  (wave-local rows) ===========
  {
    f32x4 accl[2] = {(f32x4){0,0,0,0}, (f32x4){0,0,0,0}};
    const int alo = (wid * 16 + l15) * 264 + g * 8;
    const int blo = l15 * 136 + g * 8;
    #pragma unroll
    for (int ks = 0; ks < 4; ++ks) {
      u16x8 a  = *(const u16x8*)(fz + alo + ks * 32);
      u16x8 q0 = *(const u16x8*)(mks + blo + ks * 32);
      u16x8 q1 = *(const u16x8*)(mks + blo + 16 * 136 + ks * 32);
      accl[0] = mfma16(a, q0, accl[0]);
      accl[1] = mfma16(a, q1, accl[1]);
    }
    #pragma unroll
    for (int n = 0; n < 2; ++n)
      #pragma unroll
      for (int j = 0; j < 4; ++j)
        lgs[(wid * 16 + g * 4 + j) * 33 + n * 16 + l15] = accl[n][j] * (1.0f / 0.7f);
  }

  // =========== top-2 + 2-way softmax + mem (wave-local rows) ===========
  {
    int row = tid >> 2, q = tid & 3;
    const float* lp = lgs + row * 33 + q * 8;
    float m1 = -3.4e38f, m2 = -3.4e38f; int i1 = -1, i2 = -1;
    #pragma unroll
    for (int s = 0; s < 8; ++s) {
      float v = lp[s]; int idx = q * 8 + s;
      if (v > m1) { m2 = m1; i2 = i1; m1 = v; i1 = idx; }
      else if (v > m2) { m2 = v; i2 = idx; }
    }
    #pragma unroll
    for (int d = 1; d <= 2; d <<= 1) {
      float om1 = __shfl_xor(m1, d); int oi1 = __shfl_xor(i1, d);
      float om2 = __shfl_xor(m2, d); int oi2 = __shfl_xor(i2, d);
      bool take = (om1 > m1) || (om1 == m1 && oi1 < i1);
      if (take) {
        float nm2; int ni2;
        if (m1 > om2 || (m1 == om2 && i1 < oi2)) { nm2 = m1; ni2 = i1; }
        else { nm2 = om2; ni2 = oi2; }
        m1 = om1; i1 = oi1; m2 = nm2; i2 = ni2;
      } else {
        if (om1 > m2 || (om1 == m2 && oi1 < i2)) { m2 = om1; i2 = oi1; }
      }
    }
    float a1 = 1.0f / (1.0f + expf(m2 - m1));
    float a2 = 1.0f - a1;
    const float4* v1 = (const float4*)(mvw + i1 * 128 + q * 32);
    const float4* v2 = (const float4*)(mvw + i2 * 128 + q * 32);
    #pragma unroll
    for (int c = 0; c < 4; ++c) {
      float4 pa = v1[c * 2], pb = v1[c * 2 + 1];
      float4 ra = v2[c * 2], rb = v2[c * 2 + 1];
      u16x8 o;
      o[0] = f2bf(a1 * pa.x + a2 * ra.x); o[1] = f2bf(a1 * pa.y + a2 * ra.y);
      o[2] = f2bf(a1 * pa.z + a2 * ra.z); o[3] = f2bf(a1 * pa.w + a2 * ra.w);
      o[4] = f2bf(a1 * pb.x + a2 * rb.x); o[5] = f2bf(a1 * pb.y + a2 * rb.y);
      o[6] = f2bf(a1 * pb.z + a2 * rb.z); o[7] = f2bf(a1 * pb.w + a2 * rb.w);
      *(u16x8*)(fz + row * 264 + 128 + q * 32 + c * 8) = o;
    }
  }
  __syncthreads();                    // mem visible to all

  // =========== GEMM3: h = gelu(fused @ w3 + b3)  [64 x 384], K=256, BK=32, no barriers ===========
  f32x4 acc3[4][6];
  #pragma unroll
  for (int m = 0; m < 4; ++m)
    #pragma unroll
    for (int n = 0; n < 6; ++n) acc3[m][n] = (f32x4){0.f, 0.f, 0.f, 0.f};
  for (int kt = 0; kt < 8; ++kt) {
    WAIT_VM0;                         // my tile kt landed
    u16x8 a3f[4], b3f[6];
    #pragma unroll
    for (int m = 0; m < 4; ++m)
      a3f[m] = *(const u16x8*)(fz + (m * 16 + l15) * 264 + kt * 32 + g * 8);
    #pragma unroll
    for (int n = 0; n < 6; ++n)
      b3f[n] = *(const u16x8*)(w3t + (wid * 96 + n * 16 + l15) * 32 + g * 8);
    WAIT_LGKM0;
    if (kt < 7) {
      const u16* s3 = w3s + (kt + 1) * 12288 + wid * 3072 + lane * 8;
      u16* d3 = w3t + wid * 3072;
      #pragma unroll
      for (int i = 0; i < 6; ++i) gload16(s3 + i * 512, d3 + i * 512);
    }
    __builtin_amdgcn_s_setprio(1);
    #pragma unroll
    for (int m = 0; m < 4; ++m)
      #pragma unroll
      for (int n = 0; n < 6; ++n) acc3[m][n] = mfma16(a3f[m], b3f[n], acc3[m][n]);
    __builtin_amdgcn_s_setprio(0);
  }
  __syncthreads();                    // fz reads done -> rowpart may alias

  // epilogue: per-row dot with w4, 16-lane shuffle reduce
  #pragma unroll
  for (int m = 0; m < 4; ++m) {
    float s0 = 0.f, s1 = 0.f, s2 = 0.f, s3 = 0.f;
    #pragma unroll
    for (int n = 0; n < 6; ++n) {
      int col = wid * 96 + n * 16 + l15;
      float bias = b3s[col], wv = w4s[col];
      s0 += gelu_exact(acc3[m][n][0] + bias) * wv;
      s1 += gelu_exact(acc3[m][n][1] + bias) * wv;
      s2 += gelu_exact(acc3[m][n][2] + bias) * wv;
      s3 += gelu_exact(acc3[m][n][3] + bias) * wv;
    }
    #pragma unroll
    for (int d = 1; d < 16; d <<= 1) {
      s0 += __shfl_xor(s0, d); s1 += __shfl_xor(s1, d);
      s2 += __shfl_xor(s2, d); s3 += __shfl_xor(s3, d);
    }
    if (l15 == 0) {
      int rb = m * 16 + g * 4;
      rowpart[(rb + 0) * 4 + wid] = s0;
      rowpart[(rb + 1) * 4 + wid] = s1;
      rowpart[(rb + 2) * 4 + wid] = s2;
      rowpart[(rb + 3) * 4 + wid] = s3;
    }
  }
  __syncthreads();
  if (tid < BM) {
    float lg = rowpart[tid * 4] + rowpart[tid * 4 + 1] + rowpart[tid * 4 + 2] +
               rowpart[tid * 4 + 3] + b4[0];
    out[row0 + tid] = 1.0f / (1.0f + expf(-lg));
  }
}

// ---------------- launch ----------------
extern "C" void kernel_launch(void* const* d_in, const int* in_sizes, int n_in,
                              void* d_out, int out_size, void* d_ws, size_t ws_size,
                              hipStream_t stream) {
  const float* x  = (const float*)d_in[0];
  const float* w1 = (const float*)d_in[1];
  const float* b1 = (const float*)d_in[2];
  const float* w2 = (const float*)d_in[3];
  const float* b2 = (const float*)d_in[4];
  const float* mk = (const float*)d_in[5];
  const float* mv = (const float*)d_in[6];
  const float* w3 = (const float*)d_in[7];
  const float* b3 = (const float*)d_in[8];
  const float* w4 = (const float*)d_in[9];
  const float* b4 = (const float*)d_in[10];

  u16* w1s = (u16*)d_ws;            // 393216 u16 (32 plain [384][32] tiles)
  u16* w2s = w1s + 393216;          // 49152 (12 [128][32] tiles)
  u16* w3s = w1s + 442368;          // 98304 (8 [384][32] tiles)

  prep_kernel<<<2112, 256, 0, stream>>>(w1, w2, w3, w1s, w2s, w3s);

  (void)hipFuncSetAttribute(reinterpret_cast<const void*>(fused_kernel),
                            hipFuncAttributeMaxDynamicSharedMemorySize, SMEM_BYTES);
  fused_kernel<<<NBLK, BDIM, SMEM_BYTES, stream>>>(x, w1s, b1, w2s, b2, mk, mv, w3s,
                                                   b3, w4, b4, (float*)d_out);
}

// Round 5
// 284.344 us; speedup vs baseline: 1.1234x; 1.1234x over previous
//
#include <hip/hip_runtime.h>

// ---------------- constants ----------------
#define BATCH   131072
#define INDIM   1024
#define BM      64
#define BDIM    512
#define NBLK    (BATCH / BM)          // 2048

// ---- LDS layout (bytes), phase-multiplexed ----
#define WT0_OFF  0                    // GEMM1 w-tile buf0 [384][32] bf16 (24576)
#define WT1_OFF  24576                // buf1 -> 49152
#define XT0_OFF  49152                // x-tile buf0 [64][32] (4096)
#define XT1_OFF  53248                // buf1 -> 57344
#define Z1_OFF   0                    // z1 [64][392] bf16 (50176)
#define W2T0_OFF 50176                // w2 tile buf0 [128][32] (8192)
#define W2T1_OFF 58368                // buf1 -> 66560
#define FZ_OFF   0                    // fused [64][264] bf16 (33792)
#define LG_OFF   33792                // logits [64][33] f32 (8448) -> 42240
#define RP_OFF   33792                // rowpart [64][8] f32 (aliases lgs, late)
#define W3T_OFF  42240                // w3 tile [384][32] (24576) -> 66816
#define CB_OFF   68096
#define B1S_OFF  (CB_OFF)             // 384 f32 -> +1536
#define B2S_OFF  (CB_OFF + 1536)      // 128 f32 -> +512
#define B3S_OFF  (CB_OFF + 2048)      // 384 f32 -> +1536
#define W4S_OFF  (CB_OFF + 3584)      // 384 f32 -> +1536
#define MKS_OFF  (CB_OFF + 5120)      // mk bf16 [32][136] (8704) -> 81920
#define SMEM_BYTES 81920              // 2 blocks/CU (2x81920 = 163840 = LDS cap)

typedef unsigned short u16;
typedef u16    u16x8  __attribute__((ext_vector_type(8)));
typedef u16    u16x4  __attribute__((ext_vector_type(4)));
typedef __bf16 bf16x8 __attribute__((ext_vector_type(8)));
typedef __bf16 bf16x4 __attribute__((ext_vector_type(4)));
typedef float  f32x4  __attribute__((ext_vector_type(4)));

__device__ __forceinline__ u16 f2bf(float f) {
  unsigned u = __float_as_uint(f);
  u += 0x7FFFu + ((u >> 16) & 1u);    // RNE
  return (u16)(u >> 16);
}

__device__ __forceinline__ float gelu_exact(float v) {
  return 0.5f * v * (1.0f + erff(v * 0.70710678118654752440f));
}

__device__ __forceinline__ f32x4 mfma16(u16x8 a, u16x8 b, f32x4 c) {
  return __builtin_amdgcn_mfma_f32_16x16x32_bf16(
      __builtin_bit_cast(bf16x8, a), __builtin_bit_cast(bf16x8, b), c, 0, 0, 0);
}

__device__ __forceinline__ u16x8 cvt8(float4 a, float4 b) {
  bf16x8 r;
  r[0]=(__bf16)a.x; r[1]=(__bf16)a.y; r[2]=(__bf16)a.z; r[3]=(__bf16)a.w;
  r[4]=(__bf16)b.x; r[5]=(__bf16)b.y; r[6]=(__bf16)b.z; r[7]=(__bf16)b.w;
  return __builtin_bit_cast(u16x8, r);
}
__device__ __forceinline__ u16x4 cvt4(float4 a) {
  bf16x4 r;
  r[0]=(__bf16)a.x; r[1]=(__bf16)a.y; r[2]=(__bf16)a.z; r[3]=(__bf16)a.w;
  return __builtin_bit_cast(u16x4, r);
}

typedef __attribute__((address_space(3))) unsigned int       lds_u32;
typedef __attribute__((address_space(1))) const unsigned int glb_u32;
__device__ __forceinline__ void gload16(const void* g, void* l) {
  __builtin_amdgcn_global_load_lds((glb_u32*)g, (lds_u32*)l, 16, 0, 0);
}

#define FENCE_SCHED __builtin_amdgcn_sched_barrier(0)
#define WAIT_LGKM0 do { asm volatile("s_waitcnt lgkmcnt(0)" ::: "memory"); FENCE_SCHED; } while (0)
#define WAIT_VMN(N) do { \
  asm volatile("s_waitcnt vmcnt(" #N ")" ::: "memory"); FENCE_SCHED; } while (0)
#define BARRIER_VMN(N) do { \
  asm volatile("s_waitcnt vmcnt(" #N ") lgkmcnt(0)" ::: "memory"); \
  __builtin_amdgcn_s_barrier(); FENCE_SCHED; } while (0)

// ---------------- prep: bf16-cast + transpose into chunk-swizzled [N][32] K-tiles ----
// stored chunk cp (8 u16) of row r holds source k-chunk cp ^ ((r>>1)&3)
__global__ void prep_kernel(const float* __restrict__ w1, const float* __restrict__ w2,
                            const float* __restrict__ w3, u16* __restrict__ w1s,
                            u16* __restrict__ w2s, u16* __restrict__ w3s) {
  int i = blockIdx.x * 256 + threadIdx.x;
  if (i < 393216) {                       // 32 tiles [384][32]
    int t = i / 12288, p = i % 12288;
    int r = p >> 5, q = p & 31, cp = q >> 3, o = q & 7;
    int k = t * 32 + ((cp ^ ((r >> 1) & 3)) << 3) + o;
    w1s[i] = f2bf(w1[k * 384 + r]);
  } else if (i < 442368) {                // 12 tiles [128][32]
    int j = i - 393216;
    int t = j / 4096, p = j % 4096;
    int r = p >> 5, q = p & 31, cp = q >> 3, o = q & 7;
    int k = t * 32 + ((cp ^ ((r >> 1) & 3)) << 3) + o;
    w2s[j] = f2bf(w2[k * 128 + r]);
  } else if (i < 540672) {                // 8 tiles [384][32]
    int j = i - 442368;
    int t = j / 12288, p = j % 12288;
    int r = p >> 5, q = p & 31, cp = q >> 3, o = q & 7;
    int k = t * 32 + ((cp ^ ((r >> 1) & 3)) << 3) + o;
    w3s[j] = f2bf(w3[k * 384 + r]);
  }
}

// ---------------- fused forward ----------------
__global__ __launch_bounds__(BDIM, 4) void fused_kernel(
    const float* __restrict__ x,  const u16* __restrict__ w1s,
    const float* __restrict__ b1, const u16* __restrict__ w2s,
    const float* __restrict__ b2, const float* __restrict__ mkw,
    const float* __restrict__ mvw, const u16* __restrict__ w3s,
    const float* __restrict__ b3, const float* __restrict__ w4,
    const float* __restrict__ b4, float* __restrict__ out) {
  extern __shared__ char smem[];
  u16*   z1  = (u16*)(smem + Z1_OFF);
  u16*   fz  = (u16*)(smem + FZ_OFF);
  float* lgs = (float*)(smem + LG_OFF);
  u16*   w3t = (u16*)(smem + W3T_OFF);
  float* b1s = (float*)(smem + B1S_OFF);
  float* b2s = (float*)(smem + B2S_OFF);
  float* b3s = (float*)(smem + B3S_OFF);
  float* w4s = (float*)(smem + W4S_OFF);
  u16*   mks = (u16*)(smem + MKS_OFF);
  float* rowpart = (float*)(smem + RP_OFF);

  const int tid  = threadIdx.x;
  const int lane = tid & 63;
  const int wid  = tid >> 6;          // 0..7 == waveN
  const int l15  = lane & 15;
  const int g    = lane >> 4;         // 0..3 (K chunk)
  const int xsw8 = (g ^ ((l15 >> 1) & 3)) * 8;   // swizzled chunk byte-octet
  const int row0 = blockIdx.x * BM;
  const int wstrip = wid * 1536;      // 48-row strip in [384][32] tiles (u16)
  const int wrow   = wid * 48;

  // ---------- GEMM1 prologue ----------
  {   // tile-0 w DMA (own 48-row strip)
    const u16* ws = w1s + wstrip + lane * 8;
    u16* wd = (u16*)(smem + WT0_OFF) + wstrip;
    gload16(ws, wd); gload16(ws + 512, wd + 512); gload16(ws + 1024, wd + 1024);
  }
  const int xrow = tid >> 3, xq = tid & 7;       // 1 float4 per thread per tile
  const float* xp = x + (long)(row0 + xrow) * INDIM + xq * 4;
  const int xpub = xrow * 32 + (((xq >> 1) ^ ((xrow >> 1) & 3)) << 3) + (xq & 1) * 4;
  float4 xr = *(const float4*)xp;

  for (int i = tid; i < 384; i += BDIM) b1s[i] = b1[i];
  if (tid < 128) b2s[tid] = b2[tid];
  for (int i = tid; i < 384; i += BDIM) b3s[i] = b3[i];
  for (int i = tid; i < 384; i += BDIM) w4s[i] = w4[i];
  {
    int r = tid >> 4, cc = (tid & 15) * 8;       // mk: 32 x 128
    const float4* p = (const float4*)(mkw + r * 128 + cc);
    float4 a = p[0], b = p[1];
    *(u16x8*)(mks + r * 136 + cc) = cvt8(a, b);
  }
  *(u16x4*)((u16*)(smem + XT0_OFF) + xpub) = cvt4(xr);   // publish xt[0]
  {   // tile-1 w DMA
    const u16* ws = w1s + 12288 + wstrip + lane * 8;
    u16* wd = (u16*)(smem + WT1_OFF) + wstrip;
    gload16(ws, wd); gload16(ws + 512, wd + 512); gload16(ws + 1024, wd + 1024);
  }
  xr = *(const float4*)(xp + 32);                        // x(1)
  BARRIER_VMN(4);   // tile-0 landed; xt[0] published; tile-1 + x(1) in flight

  // =========== GEMM1: z1 = gelu(x @ w1 + b1)  [64 x 384], K=1024, BK=32 ===========
  f32x4 acc[4][3];
  #pragma unroll
  for (int m = 0; m < 4; ++m)
    #pragma unroll
    for (int n = 0; n < 3; ++n) acc[m][n] = (f32x4){0.f, 0.f, 0.f, 0.f};

#define G1_STEP(KT, XB, WB, XN, DO_PF, LAST_VMN)                                 \
  do {                                                                           \
    const u16* xb = (const u16*)(smem + (XB));                                   \
    const u16* wb = (const u16*)(smem + (WB));                                   \
    u16x8 af[4], bfr[3];                                                         \
    _Pragma("unroll")                                                            \
    for (int m = 0; m < 4; ++m)                                                  \
      af[m] = *(const u16x8*)(xb + (m * 16 + l15) * 32 + xsw8);                  \
    _Pragma("unroll")                                                            \
    for (int n = 0; n < 3; ++n)                                                  \
      bfr[n] = *(const u16x8*)(wb + (wrow + n * 16 + l15) * 32 + xsw8);          \
    WAIT_LGKM0;                                                                  \
    if (DO_PF) {                                                                 \
      const u16* ws = w1s + ((KT) + 2) * 12288 + wstrip + lane * 8;              \
      u16* wd = (u16*)(smem + (WB)) + wstrip;                                    \
      gload16(ws, wd); gload16(ws + 512, wd + 512); gload16(ws + 1024, wd + 1024); \
      *(u16x4*)((u16*)(smem + (XN)) + xpub) = cvt4(xr);                          \
      xr = *(const float4*)(xp + ((KT) + 2) * 32);                               \
    }                                                                            \
    _Pragma("unroll")                                                            \
    for (int m = 0; m < 4; ++m)                                                  \
      _Pragma("unroll")                                                          \
      for (int n = 0; n < 3; ++n) acc[m][n] = mfma16(af[m], bfr[n], acc[m][n]);  \
  } while (0)

  for (int kt = 0; kt < 30; kt += 2) {
    G1_STEP(kt,     XT0_OFF, WT0_OFF, XT1_OFF, 1, 4);
    BARRIER_VMN(4);
    G1_STEP(kt + 1, XT1_OFF, WT1_OFF, XT0_OFF, 1, 4);
    BARRIER_VMN(4);
  }
  {   // kt = 30: no prefetch; publish xt[31]
    const u16* xb = (const u16*)(smem + XT0_OFF);
    const u16* wb = (const u16*)(smem + WT0_OFF);
    u16x8 af[4], bfr[3];
    #pragma unroll
    for (int m = 0; m < 4; ++m) af[m] = *(const u16x8*)(xb + (m * 16 + l15) * 32 + xsw8);
    #pragma unroll
    for (int n = 0; n < 3; ++n) bfr[n] = *(const u16x8*)(wb + (wrow + n * 16 + l15) * 32 + xsw8);
    WAIT_LGKM0;
    *(u16x4*)((u16*)(smem + XT1_OFF) + xpub) = cvt4(xr);
    #pragma unroll
    for (int m = 0; m < 4; ++m)
      #pragma unroll
      for (int n = 0; n < 3; ++n) acc[m][n] = mfma16(af[m], bfr[n], acc[m][n]);
    BARRIER_VMN(0);
  }
  {   // kt = 31
    const u16* xb = (const u16*)(smem + XT1_OFF);
    const u16* wb = (const u16*)(smem + WT1_OFF);
    u16x8 af[4], bfr[3];
    #pragma unroll
    for (int m = 0; m < 4; ++m) af[m] = *(const u16x8*)(xb + (m * 16 + l15) * 32 + xsw8);
    #pragma unroll
    for (int n = 0; n < 3; ++n) bfr[n] = *(const u16x8*)(wb + (wrow + n * 16 + l15) * 32 + xsw8);
    WAIT_LGKM0;
    #pragma unroll
    for (int m = 0; m < 4; ++m)
      #pragma unroll
      for (int n = 0; n < 3; ++n) acc[m][n] = mfma16(af[m], bfr[n], acc[m][n]);
  }
  __syncthreads();                    // staging reads done -> z1 region reusable

  // GEMM2 tiles 0,1 DMA (land under z1 epilogue)
  {
    const u16* s2 = w2s + wid * 512 + lane * 8;
    gload16(s2, (u16*)(smem + W2T0_OFF) + wid * 512);
    const u16* s2b = w2s + 4096 + wid * 512 + lane * 8;
    gload16(s2b, (u16*)(smem + W2T1_OFF) + wid * 512);
  }
  // z1 epilogue
  #pragma unroll
  for (int m = 0; m < 4; ++m) {
    #pragma unroll
    for (int n = 0; n < 3; ++n) {
      int col = wrow + n * 16 + l15;
      float bias = b1s[col];
      #pragma unroll
      for (int j = 0; j < 4; ++j)
        z1[(m * 16 + g * 4 + j) * 392 + col] = f2bf(gelu_exact(acc[m][n][j] + bias));
    }
  }
  __syncthreads();                    // z1 published

  // =========== GEMM2: z = gelu(z1 @ w2 + b2)  [64 x 128], K=384, BK=32, no barriers ===========
  f32x4 acc2[4];
  #pragma unroll
  for (int m = 0; m < 4; ++m) acc2[m] = (f32x4){0.f, 0.f, 0.f, 0.f};
  for (int kt = 0; kt < 11; ++kt) {
    WAIT_VMN(1);                      // my tile kt landed (kt+1 may fly)
    const u16* wbuf = (const u16*)(smem + W2T0_OFF + (kt & 1) * 8192);
    u16x8 a2f[4], b2f;
    #pragma unroll
    for (int m = 0; m < 4; ++m)
      a2f[m] = *(const u16x8*)(z1 + (m * 16 + l15) * 392 + kt * 32 + g * 8);
    b2f = *(const u16x8*)(wbuf + (wid * 16 + l15) * 32 + xsw8);
    WAIT_LGKM0;
    if (kt < 10) {
      const u16* s2 = w2s + (kt + 2) * 4096 + wid * 512 + lane * 8;
      gload16(s2, (u16*)(smem + W2T0_OFF + (kt & 1) * 8192) + wid * 512);
    }
    #pragma unroll
    for (int m = 0; m < 4; ++m) acc2[m] = mfma16(a2f[m], b2f, acc2[m]);
  }
  {   // kt = 11
    WAIT_VMN(0);
    const u16* wbuf = (const u16*)(smem + W2T1_OFF);
    u16x8 a2f[4], b2f;
    #pragma unroll
    for (int m = 0; m < 4; ++m)
      a2f[m] = *(const u16x8*)(z1 + (m * 16 + l15) * 392 + 352 + g * 8);
    b2f = *(const u16x8*)(wbuf + (wid * 16 + l15) * 32 + xsw8);
    WAIT_LGKM0;
    #pragma unroll
    for (int m = 0; m < 4; ++m) acc2[m] = mfma16(a2f[m], b2f, acc2[m]);
  }
  __syncthreads();                    // z1/w2t reads done -> fz & w3t regions usable

  // GEMM3 tile-0 DMA very early (covered by fz epilogue + logits + top2)
  {
    const u16* s3 = w3s + wstrip + lane * 8;
    u16* d3 = w3t + wstrip;
    gload16(s3, d3); gload16(s3 + 512, d3 + 512); gload16(s3 + 1024, d3 + 1024);
  }
  // fz epilogue (z part, cols wid*16..)
  #pragma unroll
  for (int m = 0; m < 4; ++m) {
    int col = wid * 16 + l15;
    float bias = b2s[col];
    #pragma unroll
    for (int j = 0; j < 4; ++j)
      fz[(m * 16 + g * 4 + j) * 264 + col] = f2bf(gelu_exact(acc2[m][j] + bias));
  }
  __syncthreads();                    // fz(z) published

  // =========== logits = (z @ mk^T)/tau  [64 x 32]  (waves 0..3) ===========
  if (wid < 4) {
    f32x4 accl[2] = {(f32x4){0,0,0,0}, (f32x4){0,0,0,0}};
    const int alo = (wid * 16 + l15) * 264 + g * 8;
    const int blo = l15 * 136 + g * 8;
    #pragma unroll
    for (int ks = 0; ks < 4; ++ks) {
      u16x8 a  = *(const u16x8*)(fz + alo + ks * 32);
      u16x8 q0 = *(const u16x8*)(mks + blo + ks * 32);
      u16x8 q1 = *(const u16x8*)(mks + blo + 2176 + ks * 32);
      accl[0] = mfma16(a, q0, accl[0]);
      accl[1] = mfma16(a, q1, accl[1]);
    }
    #pragma unroll
    for (int n = 0; n < 2; ++n)
      #pragma unroll
      for (int j = 0; j < 4; ++j)
        lgs[(wid * 16 + g * 4 + j) * 33 + n * 16 + l15] = accl[n][j] * (1.0f / 0.7f);
  }
  __syncthreads();

  // =========== top-2 + 2-way softmax + mem (8 threads/row) ===========
  {
    int row = tid >> 3, q = tid & 7;
    const float* lp = lgs + row * 33 + q * 4;
    float m1 = -3.4e38f, m2 = -3.4e38f; int i1 = -1, i2 = -1;
    #pragma unroll
    for (int s = 0; s < 4; ++s) {
      float v = lp[s]; int idx = q * 4 + s;
      if (v > m1) { m2 = m1; i2 = i1; m1 = v; i1 = idx; }
      else if (v > m2) { m2 = v; i2 = idx; }
    }
    #pragma unroll
    for (int d = 1; d <= 4; d <<= 1) {
      float om1 = __shfl_xor(m1, d); int oi1 = __shfl_xor(i1, d);
      float om2 = __shfl_xor(m2, d); int oi2 = __shfl_xor(i2, d);
      bool take = (om1 > m1) || (om1 == m1 && oi1 < i1);
      if (take) {
        float nm2; int ni2;
        if (m1 > om2 || (m1 == om2 && i1 < oi2)) { nm2 = m1; ni2 = i1; }
        else { nm2 = om2; ni2 = oi2; }
        m1 = om1; i1 = oi1; m2 = nm2; i2 = ni2;
      } else {
        if (om1 > m2 || (om1 == m2 && oi1 < i2)) { m2 = om1; i2 = oi1; }
      }
    }
    float a1 = 1.0f / (1.0f + expf(m2 - m1));
    float a2 = 1.0f - a1;
    const float4* v1 = (const float4*)(mvw + i1 * 128 + q * 16);
    const float4* v2 = (const float4*)(mvw + i2 * 128 + q * 16);
    float4 pa = v1[0], pb = v1[1], ra = v2[0], rb = v2[1];
    u16x8 o;
    o[0]=f2bf(a1*pa.x+a2*ra.x); o[1]=f2bf(a1*pa.y+a2*ra.y);
    o[2]=f2bf(a1*pa.z+a2*ra.z); o[3]=f2bf(a1*pa.w+a2*ra.w);
    o[4]=f2bf(a1*pb.x+a2*rb.x); o[5]=f2bf(a1*pb.y+a2*rb.y);
    o[6]=f2bf(a1*pb.z+a2*rb.z); o[7]=f2bf(a1*pb.w+a2*rb.w);
    *(u16x8*)(fz + row * 264 + 128 + q * 16) = o;
    pa = v1[2]; pb = v1[3]; ra = v2[2]; rb = v2[3];
    o[0]=f2bf(a1*pa.x+a2*ra.x); o[1]=f2bf(a1*pa.y+a2*ra.y);
    o[2]=f2bf(a1*pa.z+a2*ra.z); o[3]=f2bf(a1*pa.w+a2*ra.w);
    o[4]=f2bf(a1*pb.x+a2*rb.x); o[5]=f2bf(a1*pb.y+a2*rb.y);
    o[6]=f2bf(a1*pb.z+a2*rb.z); o[7]=f2bf(a1*pb.w+a2*rb.w);
    *(u16x8*)(fz + row * 264 + 128 + q * 16 + 8) = o;
  }
  __syncthreads();                    // mem visible to all

  // =========== GEMM3: h = gelu(fused @ w3 + b3)  [64 x 384], K=256, BK=32, no barriers ===========
  f32x4 acc3[4][3];
  #pragma unroll
  for (int m = 0; m < 4; ++m)
    #pragma unroll
    for (int n = 0; n < 3; ++n) acc3[m][n] = (f32x4){0.f, 0.f, 0.f, 0.f};
  for (int kt = 0; kt < 8; ++kt) {
    WAIT_VMN(0);                      // my tile kt landed
    u16x8 a3f[4], b3f[3];
    #pragma unroll
    for (int m = 0; m < 4; ++m)
      a3f[m] = *(const u16x8*)(fz + (m * 16 + l15) * 264 + kt * 32 + g * 8);
    #pragma unroll
    for (int n = 0; n < 3; ++n)
      b3f[n] = *(const u16x8*)(w3t + (wrow + n * 16 + l15) * 32 + xsw8);
    WAIT_LGKM0;
    if (kt < 7) {
      const u16* s3 = w3s + (kt + 1) * 12288 + wstrip + lane * 8;
      u16* d3 = w3t + wstrip;
      gload16(s3, d3); gload16(s3 + 512, d3 + 512); gload16(s3 + 1024, d3 + 1024);
    }
    #pragma unroll
    for (int m = 0; m < 4; ++m)
      #pragma unroll
      for (int n = 0; n < 3; ++n) acc3[m][n] = mfma16(a3f[m], b3f[n], acc3[m][n]);
  }

  // epilogue: per-row dot with w4, 16-lane shuffle reduce
  #pragma unroll
  for (int m = 0; m < 4; ++m) {
    float s0 = 0.f, s1 = 0.f, s2 = 0.f, s3 = 0.f;
    #pragma unroll
    for (int n = 0; n < 3; ++n) {
      int col = wrow + n * 16 + l15;
      float bias = b3s[col], wv = w4s[col];
      s0 += gelu_exact(acc3[m][n][0] + bias) * wv;
      s1 += gelu_exact(acc3[m][n][1] + bias) * wv;
      s2 += gelu_exact(acc3[m][n][2] + bias) * wv;
      s3 += gelu_exact(acc3[m][n][3] + bias) * wv;
    }
    #pragma unroll
    for (int d = 1; d < 16; d <<= 1) {
      s0 += __shfl_xor(s0, d); s1 += __shfl_xor(s1, d);
      s2 += __shfl_xor(s2, d); s3 += __shfl_xor(s3, d);
    }
    if (l15 == 0) {
      int rb = m * 16 + g * 4;
      rowpart[(rb + 0) * 8 + wid] = s0;
      rowpart[(rb + 1) * 8 + wid] = s1;
      rowpart[(rb + 2) * 8 + wid] = s2;
      rowpart[(rb + 3) * 8 + wid] = s3;
    }
  }
  __syncthreads();
  if (tid < BM) {
    float lg = b4[0];
    #pragma unroll
    for (int w = 0; w < 8; ++w) lg += rowpart[tid * 8 + w];
    out[row0 + tid] = 1.0f / (1.0f + expf(-lg));
  }
}

// ---------------- launch ----------------
extern "C" void kernel_launch(void* const* d_in, const int* in_sizes, int n_in,
                              void* d_out, int out_size, void* d_ws, size_t ws_size,
                              hipStream_t stream) {
  const float* x  = (const float*)d_in[0];
  const float* w1 = (const float*)d_in[1];
  const float* b1 = (const float*)d_in[2];
  const float* w2 = (const float*)d_in[3];
  const float* b2 = (const float*)d_in[4];
  const float* mk = (const float*)d_in[5];
  const float* mv = (const float*)d_in[6];
  const float* w3 = (const float*)d_in[7];
  const float* b3 = (const float*)d_in[8];
  const float* w4 = (const float*)d_in[9];
  const float* b4 = (const float*)d_in[10];

  u16* w1s = (u16*)d_ws;            // 393216 u16 (32 swizzled [384][32] tiles)
  u16* w2s = w1s + 393216;          // 49152 (12 [128][32] tiles)
  u16* w3s = w1s + 442368;          // 98304 (8 [384][32] tiles)

  prep_kernel<<<2112, 256, 0, stream>>>(w1, w2, w3, w1s, w2s, w3s);

  (void)hipFuncSetAttribute(reinterpret_cast<const void*>(fused_kernel),
                            hipFuncAttributeMaxDynamicSharedMemorySize, SMEM_BYTES);
  fused_kernel<<<NBLK, BDIM, SMEM_BYTES, stream>>>(x, w1s, b1, w2s, b2, mk, mv, w3s,
                                                   b3, w4, b4, (float*)d_out);
}

// Round 6
// 231.762 us; speedup vs baseline: 1.3783x; 1.2269x over previous
//
#include <hip/hip_runtime.h>

// ---------------- constants ----------------
#define BATCH   131072
#define INDIM   1024
#define BM      64
#define BDIM    512
#define NBLK    (BATCH / BM)          // 2048

// ---- LDS layout (bytes), phase-multiplexed ----
#define WT_OFF   0                    // G1 w-tile [384][64] bf16 (49152), wave-private strips
#define XT0_OFF  49152                // x-tile buf0 [64][64] bf16 (8192)
#define XT1_OFF  57344                // buf1 -> 65536
#define Z1_OFF   0                    // z1 [64][392] bf16 (50176)
#define W2T0_OFF 50176                // w2 strip-tile buf0 [128][32] (8192)
#define W2T1_OFF 58368                // buf1 -> 66560
#define FZ_OFF   0                    // fused [64][264] bf16 (33792)
#define RP_OFF   33792                // rowpart [64][8] f32 (2048)
#define W3T_OFF  42240                // w3 tile [384][32] (24576) -> 66816
#define CB_OFF   66816
#define B1S_OFF  (CB_OFF)             // 384 f32
#define B2S_OFF  (CB_OFF + 1536)      // 128 f32
#define B3S_OFF  (CB_OFF + 2048)      // 384 f32
#define W4S_OFF  (CB_OFF + 3584)      // 384 f32
#define MKS_OFF  (CB_OFF + 5120)      // mk bf16 [32][136] (8704)
#define SMEM_BYTES (CB_OFF + 13824)   // 80640 -> 2 blocks/CU

typedef unsigned short u16;
typedef u16    u16x8  __attribute__((ext_vector_type(8)));
typedef u16    u16x4  __attribute__((ext_vector_type(4)));
typedef __bf16 bf16x8 __attribute__((ext_vector_type(8)));
typedef __bf16 bf16x4 __attribute__((ext_vector_type(4)));
typedef float  f32x4  __attribute__((ext_vector_type(4)));

__device__ __forceinline__ u16 f2bf(float f) {
  unsigned u = __float_as_uint(f);
  u += 0x7FFFu + ((u >> 16) & 1u);    // RNE
  return (u16)(u >> 16);
}

// tanh-form GELU via sigmoid: gelu(v) ~= v * sigmoid(2u), u = sqrt(2/pi)(v + 0.044715 v^3)
// max abs err vs exact ~3e-4 (budget 1e-2). 2 transcendental + ~6 VALU vs ~25 for erff.
__device__ __forceinline__ float gelu_fast(float v) {
  float t = v * v;
  float u = v * fmaf(t, 0.0356774081f, 0.7978845608f);
  float e = __builtin_amdgcn_exp2f(u * -2.885390082f);      // exp(-2u)
  return v * __builtin_amdgcn_rcpf(1.0f + e);
}

__device__ __forceinline__ f32x4 mfma16(u16x8 a, u16x8 b, f32x4 c) {
  return __builtin_amdgcn_mfma_f32_16x16x32_bf16(
      __builtin_bit_cast(bf16x8, a), __builtin_bit_cast(bf16x8, b), c, 0, 0, 0);
}

__device__ __forceinline__ u16x8 cvt8(float4 a, float4 b) {
  bf16x8 r;
  r[0]=(__bf16)a.x; r[1]=(__bf16)a.y; r[2]=(__bf16)a.z; r[3]=(__bf16)a.w;
  r[4]=(__bf16)b.x; r[5]=(__bf16)b.y; r[6]=(__bf16)b.z; r[7]=(__bf16)b.w;
  return __builtin_bit_cast(u16x8, r);
}
__device__ __forceinline__ u16x4 cvt4(float4 a) {
  bf16x4 r;
  r[0]=(__bf16)a.x; r[1]=(__bf16)a.y; r[2]=(__bf16)a.z; r[3]=(__bf16)a.w;
  return __builtin_bit_cast(u16x4, r);
}

typedef __attribute__((address_space(3))) unsigned int       lds_u32;
typedef __attribute__((address_space(1))) const unsigned int glb_u32;
__device__ __forceinline__ void gload16(const void* g, void* l) {
  __builtin_amdgcn_global_load_lds((glb_u32*)g, (lds_u32*)l, 16, 0, 0);
}

#define FENCE_SCHED __builtin_amdgcn_sched_barrier(0)
#define WAIT_LGKM0 do { asm volatile("s_waitcnt lgkmcnt(0)" ::: "memory"); FENCE_SCHED; } while (0)
#define WAIT_VMN(N) do { asm volatile("s_waitcnt vmcnt(" #N ")" ::: "memory"); FENCE_SCHED; } while (0)
// Barrier WITHOUT vmcnt drain: all cross-wave data is ds_write-published (lgkm);
// DMA'd weight strips are wave-private (own vmcnt discipline). This keeps all
// global_load_lds prefetches in flight across phase boundaries.
#define BARRIER_LGKM do { \
  asm volatile("s_waitcnt lgkmcnt(0)" ::: "memory"); \
  __builtin_amdgcn_s_barrier(); FENCE_SCHED; } while (0)

// ---------------- prep: bf16-cast + transpose into chunk-swizzled K-tiles ----------------
// w1s: 16 tiles [384 r][64 k], 16B chunk cp holds source k-chunk cp^(r&7)
// w2s: 12 tiles [128 r][32 k], cp^((r>>1)&3)
// w3s:  8 tiles [384 r][32 k], cp^((r>>1)&3)
__global__ void prep_kernel(const float* __restrict__ w1, const float* __restrict__ w2,
                            const float* __restrict__ w3, u16* __restrict__ w1s,
                            u16* __restrict__ w2s, u16* __restrict__ w3s) {
  int i = blockIdx.x * 256 + threadIdx.x;
  if (i < 393216) {
    int t = i / 24576, p = i % 24576;
    int r = p >> 6, q = p & 63, cp = q >> 3, o = q & 7;
    int k = t * 64 + ((cp ^ (r & 7)) << 3) + o;
    w1s[i] = f2bf(w1[k * 384 + r]);
  } else if (i < 442368) {
    int j = i - 393216;
    int t = j / 4096, p = j % 4096;
    int r = p >> 5, q = p & 31, cp = q >> 3, o = q & 7;
    int k = t * 32 + ((cp ^ ((r >> 1) & 3)) << 3) + o;
    w2s[j] = f2bf(w2[k * 128 + r]);
  } else if (i < 540672) {
    int j = i - 442368;
    int t = j / 12288, p = j % 12288;
    int r = p >> 5, q = p & 31, cp = q >> 3, o = q & 7;
    int k = t * 32 + ((cp ^ ((r >> 1) & 3)) << 3) + o;
    w3s[j] = f2bf(w3[k * 384 + r]);
  }
}

// ---------------- fused forward ----------------
__global__ __launch_bounds__(BDIM, 4) void fused_kernel(
    const float* __restrict__ x,  const u16* __restrict__ w1s,
    const float* __restrict__ b1, const u16* __restrict__ w2s,
    const float* __restrict__ b2, const float* __restrict__ mkw,
    const float* __restrict__ mvw, const u16* __restrict__ w3s,
    const float* __restrict__ b3, const float* __restrict__ w4,
    const float* __restrict__ b4, float* __restrict__ out) {
  extern __shared__ char smem[];
  u16*   z1  = (u16*)(smem + Z1_OFF);
  u16*   fz  = (u16*)(smem + FZ_OFF);
  u16*   w3t = (u16*)(smem + W3T_OFF);
  float* b1s = (float*)(smem + B1S_OFF);
  float* b2s = (float*)(smem + B2S_OFF);
  float* b3s = (float*)(smem + B3S_OFF);
  float* w4s = (float*)(smem + W4S_OFF);
  u16*   mks = (u16*)(smem + MKS_OFF);
  float* rowpart = (float*)(smem + RP_OFF);

  const int tid  = threadIdx.x;
  const int lane = tid & 63;
  const int wid  = tid >> 6;          // 0..7: wave owns 48 w-cols (G1/G3), 16 (G2)
  const int l15  = lane & 15;
  const int g    = lane >> 4;         // 0..3
  const int swz8 = l15 & 7;
  const int swz4 = (l15 >> 1) & 3;
  const int row0 = blockIdx.x * BM;
  const int wrow = wid * 48;
  const int wstrip = wid * 3072;      // u16 offset of 48-row strip in [384][64]

  // ---------- prologue ----------
  {   // G1 strip(0) DMA (wave-private)
    const u16* ws = w1s + wstrip + lane * 8;
    u16* wd = (u16*)(smem + WT_OFF) + wstrip;
    #pragma unroll
    for (int i = 0; i < 6; ++i) gload16(ws + i * 512, wd + i * 512);
  }
  FENCE_SCHED;
  const int xrow = tid >> 3, xoct = tid & 7;   // 32B of x per thread per K-tile
  const float* xp = x + (long)(row0 + xrow) * INDIM + xoct * 8;
  const int xdst = xrow * 64 + ((xoct ^ (xrow & 7)) << 3);
  float4 xa = *(const float4*)xp, xb = *(const float4*)(xp + 4);

  if (tid < 384) b1s[tid] = b1[tid];
  if (tid < 128) b2s[tid] = b2[tid];
  if (tid < 384) b3s[tid] = b3[tid];
  if (tid < 384) w4s[tid] = w4[tid];
  {
    int r = tid >> 4, cc = (tid & 15) * 8;
    const float4* p = (const float4*)(mkw + r * 128 + cc);
    *(u16x8*)(mks + r * 136 + cc) = cvt8(p[0], p[1]);
  }
  *(u16x8*)((u16*)(smem + XT0_OFF) + xdst) = cvt8(xa, xb);   // publish xt[0] (drains DMA0 too)
  { const float* p = xp + 64; xa = *(const float4*)p; xb = *(const float4*)(p + 4); }  // x(1)
  BARRIER_LGKM;

  // =========== GEMM1: z1 = gelu(x@w1+b1) [64x384], K=1024, BK=64 ===========
  // swapped mfma: D[wcol][xrow]; lane=l15 -> x-row, rows g*4+j -> w-cols (consecutive!)
  f32x4 acc[4][3];
  #pragma unroll
  for (int m = 0; m < 4; ++m)
    #pragma unroll
    for (int n = 0; n < 3; ++n) acc[m][n] = (f32x4){0.f, 0.f, 0.f, 0.f};

  const u16* wtb = (const u16*)(smem + WT_OFF);
  for (int kt = 0; kt < 16; ++kt) {
    if (kt < 15) { WAIT_VMN(2); } else { WAIT_VMN(0); }   // strip(kt) landed; 2 xloads fly
    const u16* xtb = (const u16*)(smem + ((kt & 1) ? XT1_OFF : XT0_OFF));
    u16x8 af[4], bfr[3];
    const int c0 = (g ^ swz8) * 8;
    #pragma unroll
    for (int m = 0; m < 4; ++m) af[m] = *(const u16x8*)(xtb + (m * 16 + l15) * 64 + c0);
    #pragma unroll
    for (int n = 0; n < 3; ++n) bfr[n] = *(const u16x8*)(wtb + (wrow + n * 16 + l15) * 64 + c0);
    #pragma unroll
    for (int m = 0; m < 4; ++m)
      #pragma unroll
      for (int n = 0; n < 3; ++n) acc[m][n] = mfma16(bfr[n], af[m], acc[m][n]);
    const int c1 = ((g + 4) ^ swz8) * 8;
    #pragma unroll
    for (int m = 0; m < 4; ++m) af[m] = *(const u16x8*)(xtb + (m * 16 + l15) * 64 + c1);
    #pragma unroll
    for (int n = 0; n < 3; ++n) bfr[n] = *(const u16x8*)(wtb + (wrow + n * 16 + l15) * 64 + c1);
    WAIT_LGKM0;                        // strip(kt) fully read -> overwrite OK
    if (kt < 15) {
      const u16* ws = w1s + (kt + 1) * 24576 + wstrip + lane * 8;
      u16* wd = (u16*)(smem + WT_OFF) + wstrip;
      #pragma unroll
      for (int i = 0; i < 6; ++i) gload16(ws + i * 512, wd + i * 512);
      FENCE_SCHED;
      u16* xn = (u16*)(smem + ((kt & 1) ? XT0_OFF : XT1_OFF));
      *(u16x8*)(xn + xdst) = cvt8(xa, xb);       // publish xt[kt+1] (auto vmcnt(6))
      if (kt < 14) {
        const float* p = xp + (kt + 2) * 64;
        xa = *(const float4*)p; xb = *(const float4*)(p + 4);
      }
      BARRIER_LGKM;                    // xt[kt+1] visible; DMAs stay in flight
    }
    #pragma unroll
    for (int m = 0; m < 4; ++m)
      #pragma unroll
      for (int n = 0; n < 3; ++n) acc[m][n] = mfma16(bfr[n], af[m], acc[m][n]);
  }
  BARRIER_LGKM;                        // all staging reads done -> region reusable

  // G2 strips 0,1 DMA (wave-private, land under z1 epilogue)
  {
    const u16* s2 = w2s + wid * 512 + lane * 8;
    gload16(s2, (u16*)(smem + W2T0_OFF) + wid * 512);
    const u16* s2b = w2s + 4096 + wid * 512 + lane * 8;
    gload16(s2b, (u16*)(smem + W2T1_OFF) + wid * 512);
  }
  // z1 epilogue: b64 writes of 4 consecutive cols
  #pragma unroll
  for (int m = 0; m < 4; ++m) {
    #pragma unroll
    for (int n = 0; n < 3; ++n) {
      int col = wrow + n * 16 + g * 4;
      float4 bv = *(const float4*)(b1s + col);
      f32x4 a = acc[m][n];
      float4 gv = {gelu_fast(a[0] + bv.x), gelu_fast(a[1] + bv.y),
                   gelu_fast(a[2] + bv.z), gelu_fast(a[3] + bv.w)};
      *(u16x4*)(z1 + (m * 16 + l15) * 392 + col) = cvt4(gv);
    }
  }
  BARRIER_LGKM;                        // z1 visible

  // =========== GEMM2: z = gelu(z1@w2+b2) [64x128], K=384, BK=32, no barriers ===========
  f32x4 acc2[4];
  #pragma unroll
  for (int m = 0; m < 4; ++m) acc2[m] = (f32x4){0.f, 0.f, 0.f, 0.f};
  for (int kt = 0; kt < 12; ++kt) {
    if (kt < 10) { WAIT_VMN(1); } else { WAIT_VMN(0); }
    const u16* wb = (const u16*)(smem + ((kt & 1) ? W2T1_OFF : W2T0_OFF));
    u16x8 a2f[4];
    #pragma unroll
    for (int m = 0; m < 4; ++m)
      a2f[m] = *(const u16x8*)(z1 + (m * 16 + l15) * 392 + kt * 32 + g * 8);
    u16x8 b2f = *(const u16x8*)(wb + (wid * 16 + l15) * 32 + (g ^ swz4) * 8);
    WAIT_LGKM0;
    if (kt < 10) {
      const u16* s2 = w2s + (kt + 2) * 4096 + wid * 512 + lane * 8;
      gload16(s2, (u16*)(smem + ((kt & 1) ? W2T1_OFF : W2T0_OFF)) + wid * 512);
    }
    #pragma unroll
    for (int m = 0; m < 4; ++m) acc2[m] = mfma16(b2f, a2f[m], acc2[m]);
  }
  BARRIER_LGKM;                        // z1/w2t dead -> fz & w3t regions usable

  // G3 strip(0) DMA early (covered by fz epilogue + logits + top2)
  {
    const u16* s3 = w3s + wid * 1536 + lane * 8;
    u16* d3 = w3t + wid * 1536;
    gload16(s3, d3); gload16(s3 + 512, d3 + 512); gload16(s3 + 1024, d3 + 1024);
  }
  // fz epilogue (z part): b64 writes
  #pragma unroll
  for (int m = 0; m < 4; ++m) {
    int col = wid * 16 + g * 4;
    float4 bv = *(const float4*)(b2s + col);
    f32x4 a = acc2[m];
    float4 gv = {gelu_fast(a[0] + bv.x), gelu_fast(a[1] + bv.y),
                 gelu_fast(a[2] + bv.z), gelu_fast(a[3] + bv.w)};
    *(u16x4*)(fz + (m * 16 + l15) * 264 + col) = cvt4(gv);
  }
  BARRIER_LGKM;                        // fz(z) visible

  // =========== logits + in-register top-2 + mem blend (waves 0..3, rows wid*16+l15) ===========
  if (wid < 4) {
    const int wr = wid * 16 + l15;
    f32x4 accl[2] = {(f32x4){0,0,0,0}, (f32x4){0,0,0,0}};
    #pragma unroll
    for (int ks = 0; ks < 4; ++ks) {
      u16x8 afz = *(const u16x8*)(fz + wr * 264 + ks * 32 + g * 8);
      u16x8 k0  = *(const u16x8*)(mks + l15 * 136 + ks * 32 + g * 8);
      u16x8 k1  = *(const u16x8*)(mks + (16 + l15) * 136 + ks * 32 + g * 8);
      accl[0] = mfma16(k0, afz, accl[0]);   // D[slot][row]: lane=row, slot=n*16+g*4+j
      accl[1] = mfma16(k1, afz, accl[1]);
    }
    float m1 = -3.4e38f, m2 = -3.4e38f; int i1 = -1, i2 = -1;
    #pragma unroll
    for (int n = 0; n < 2; ++n)
      #pragma unroll
      for (int j = 0; j < 4; ++j) {
        float v = accl[n][j]; int idx = n * 16 + g * 4 + j;
        if (v > m1) { m2 = m1; i2 = i1; m1 = v; i1 = idx; }
        else if (v > m2) { m2 = v; i2 = idx; }
      }
    #pragma unroll
    for (int d = 16; d <= 32; d <<= 1) {   // merge across g-groups (same row)
      float om1 = __shfl_xor(m1, d); int oi1 = __shfl_xor(i1, d);
      float om2 = __shfl_xor(m2, d); int oi2 = __shfl_xor(i2, d);
      bool take = (om1 > m1) || (om1 == m1 && oi1 < i1);
      if (take) {
        float nm2; int ni2;
        if (m1 > om2 || (m1 == om2 && i1 < oi2)) { nm2 = m1; ni2 = i1; }
        else { nm2 = om2; ni2 = oi2; }
        m1 = om1; i1 = oi1; m2 = nm2; i2 = ni2;
      } else {
        if (om1 > m2 || (om1 == m2 && oi1 < i2)) { m2 = om1; i2 = oi1; }
      }
    }
    // 2-way softmax (tau folded into exponent); fast exp2/rcp
    float a1 = __builtin_amdgcn_rcpf(
        1.0f + __builtin_amdgcn_exp2f((m2 - m1) * (1.44269504f / 0.7f)));
    float a2 = 1.0f - a1;
    const float* v1 = mvw + i1 * 128 + g * 32;
    const float* v2 = mvw + i2 * 128 + g * 32;
    #pragma unroll
    for (int c = 0; c < 4; ++c) {
      float4 A0 = *(const float4*)(v1 + c * 8), A1 = *(const float4*)(v1 + c * 8 + 4);
      float4 B0 = *(const float4*)(v2 + c * 8), B1 = *(const float4*)(v2 + c * 8 + 4);
      float4 r0 = {a1*A0.x + a2*B0.x, a1*A0.y + a2*B0.y, a1*A0.z + a2*B0.z, a1*A0.w + a2*B0.w};
      float4 r1 = {a1*A1.x + a2*B1.x, a1*A1.y + a2*B1.y, a1*A1.z + a2*B1.z, a1*A1.w + a2*B1.w};
      *(u16x8*)(fz + wr * 264 + 128 + g * 32 + c * 8) = cvt8(r0, r1);
    }
  }
  BARRIER_LGKM;                        // mem visible

  // =========== GEMM3: h = gelu(fused@w3+b3) [64x384], K=256, BK=32, no barriers ===========
  f32x4 acc3[4][3];
  #pragma unroll
  for (int m = 0; m < 4; ++m)
    #pragma unroll
    for (int n = 0; n < 3; ++n) acc3[m][n] = (f32x4){0.f, 0.f, 0.f, 0.f};
  for (int kt = 0; kt < 8; ++kt) {
    WAIT_VMN(0);                       // my strip(kt) landed
    u16x8 a3f[4], b3f[3];
    #pragma unroll
    for (int m = 0; m < 4; ++m)
      a3f[m] = *(const u16x8*)(fz + (m * 16 + l15) * 264 + kt * 32 + g * 8);
    #pragma unroll
    for (int n = 0; n < 3; ++n)
      b3f[n] = *(const u16x8*)(w3t + (wrow + n * 16 + l15) * 32 + (g ^ swz4) * 8);
    WAIT_LGKM0;
    if (kt < 7) {
      const u16* s3 = w3s + (kt + 1) * 12288 + wid * 1536 + lane * 8;
      u16* d3 = w3t + wid * 1536;
      gload16(s3, d3); gload16(s3 + 512, d3 + 512); gload16(s3 + 1024, d3 + 1024);
    }
    #pragma unroll
    for (int m = 0; m < 4; ++m)
      #pragma unroll
      for (int n = 0; n < 3; ++n) acc3[m][n] = mfma16(b3f[n], a3f[m], acc3[m][n]);
  }

  // epilogue: per-row dot with w4; lane holds 4 consecutive cols -> 2-step shuffle reduce
  #pragma unroll
  for (int m = 0; m < 4; ++m) {
    float s = 0.f;
    #pragma unroll
    for (int n = 0; n < 3; ++n) {
      int col = wrow + n * 16 + g * 4;
      float4 bv = *(const float4*)(b3s + col);
      float4 wv = *(const float4*)(w4s + col);
      f32x4 a = acc3[m][n];
      s += gelu_fast(a[0] + bv.x) * wv.x + gelu_fast(a[1] + bv.y) * wv.y +
           gelu_fast(a[2] + bv.z) * wv.z + gelu_fast(a[3] + bv.w) * wv.w;
    }
    s += __shfl_xor(s, 16);
    s += __shfl_xor(s, 32);
    if (lane < 16) rowpart[(m * 16 + l15) * 8 + wid] = s;
  }
  BARRIER_LGKM;
  if (tid < BM) {
    const float4* rp = (const float4*)(rowpart + tid * 8);
    float4 p0 = rp[0], p1 = rp[1];
    float lg = b4[0] + p0.x + p0.y + p0.z + p0.w + p1.x + p1.y + p1.z + p1.w;
    out[row0 + tid] = __builtin_amdgcn_rcpf(1.0f + __builtin_amdgcn_exp2f(-lg * 1.44269504f));
  }
}

// ---------------- launch ----------------
extern "C" void kernel_launch(void* const* d_in, const int* in_sizes, int n_in,
                              void* d_out, int out_size, void* d_ws, size_t ws_size,
                              hipStream_t stream) {
  const float* x  = (const float*)d_in[0];
  const float* w1 = (const float*)d_in[1];
  const float* b1 = (const float*)d_in[2];
  const float* w2 = (const float*)d_in[3];
  const float* b2 = (const float*)d_in[4];
  const float* mk = (const float*)d_in[5];
  const float* mv = (const float*)d_in[6];
  const float* w3 = (const float*)d_in[7];
  const float* b3 = (const float*)d_in[8];
  const float* w4 = (const float*)d_in[9];
  const float* b4 = (const float*)d_in[10];

  u16* w1s = (u16*)d_ws;            // 393216 u16 (16 swizzled [384][64] tiles)
  u16* w2s = w1s + 393216;          // 49152 (12 [128][32] tiles)
  u16* w3s = w1s + 442368;          // 98304 (8 [384][32] tiles)

  prep_kernel<<<2112, 256, 0, stream>>>(w1, w2, w3, w1s, w2s, w3s);

  (void)hipFuncSetAttribute(reinterpret_cast<const void*>(fused_kernel),
                            hipFuncAttributeMaxDynamicSharedMemorySize, SMEM_BYTES);
  fused_kernel<<<NBLK, BDIM, SMEM_BYTES, stream>>>(x, w1s, b1, w2s, b2, mk, mv, w3s,
                                                   b3, w4, b4, (float*)d_out);
}

// Round 7
// 229.015 us; speedup vs baseline: 1.3948x; 1.0120x over previous
//
#include <hip/hip_runtime.h>

// ---------------- constants ----------------
#define BATCH   131072
#define INDIM   1024
#define BM      64
#define BDIM    512
#define NBLK    (BATCH / BM)          // 2048

// ---- LDS layout (bytes), phase-multiplexed ----
#define WT0_OFF  0                    // G1 w-strip buf0 [384][32] bf16 (24576), wave-private
#define WT1_OFF  24576                // buf1 -> 49152
#define XTA_OFF  49152                // x-tile pair A: 2x[64][32] (8192) -> 57344
#define XTB_OFF  57344                // pair B -> 65536
#define Z1_OFF   0                    // z1 [64][392] bf16 (50176)
#define W2T0_OFF 50176                // w2 strip buf0 [128][32] (8192)
#define W2T1_OFF 58368                // buf1 -> 66560
#define FZ_OFF   0                    // fused [64][264] bf16 (33792)
#define RP_OFF   33792                // rowpart [64][8] f32 (2048)
#define W3T_OFF  42240                // w3 tile [384][32] (24576) -> 66816
#define CB_OFF   66816
#define B1S_OFF  (CB_OFF)             // 384 f32
#define B2S_OFF  (CB_OFF + 1536)      // 128 f32
#define B3S_OFF  (CB_OFF + 2048)      // 384 f32
#define W4S_OFF  (CB_OFF + 3584)      // 384 f32
#define MKS_OFF  (CB_OFF + 5120)      // mk bf16 [32][136] (8704)
#define SMEM_BYTES (CB_OFF + 13824)   // 80640 -> 2 blocks/CU

typedef unsigned short u16;
typedef u16    u16x8  __attribute__((ext_vector_type(8)));
typedef u16    u16x4  __attribute__((ext_vector_type(4)));
typedef __bf16 bf16x8 __attribute__((ext_vector_type(8)));
typedef __bf16 bf16x4 __attribute__((ext_vector_type(4)));
typedef float  f32x4  __attribute__((ext_vector_type(4)));

__device__ __forceinline__ u16 f2bf(float f) {
  unsigned u = __float_as_uint(f);
  u += 0x7FFFu + ((u >> 16) & 1u);    // RNE
  return (u16)(u >> 16);
}

// tanh-form GELU via sigmoid (max abs err ~3e-4, budget 1e-2)
__device__ __forceinline__ float gelu_fast(float v) {
  float t = v * v;
  float u = v * fmaf(t, 0.0356774081f, 0.7978845608f);
  float e = __builtin_amdgcn_exp2f(u * -2.885390082f);
  return v * __builtin_amdgcn_rcpf(1.0f + e);
}

__device__ __forceinline__ f32x4 mfma16(u16x8 a, u16x8 b, f32x4 c) {
  return __builtin_amdgcn_mfma_f32_16x16x32_bf16(
      __builtin_bit_cast(bf16x8, a), __builtin_bit_cast(bf16x8, b), c, 0, 0, 0);
}

__device__ __forceinline__ u16x8 cvt8(float4 a, float4 b) {
  bf16x8 r;
  r[0]=(__bf16)a.x; r[1]=(__bf16)a.y; r[2]=(__bf16)a.z; r[3]=(__bf16)a.w;
  r[4]=(__bf16)b.x; r[5]=(__bf16)b.y; r[6]=(__bf16)b.z; r[7]=(__bf16)b.w;
  return __builtin_bit_cast(u16x8, r);
}
__device__ __forceinline__ u16x4 cvt4(float4 a) {
  bf16x4 r;
  r[0]=(__bf16)a.x; r[1]=(__bf16)a.y; r[2]=(__bf16)a.z; r[3]=(__bf16)a.w;
  return __builtin_bit_cast(u16x4, r);
}

typedef __attribute__((address_space(3))) unsigned int       lds_u32;
typedef __attribute__((address_space(1))) const unsigned int glb_u32;
__device__ __forceinline__ void gload16(const void* g, void* l) {
  __builtin_amdgcn_global_load_lds((glb_u32*)g, (lds_u32*)l, 16, 0, 0);
}

#define FENCE_SCHED __builtin_amdgcn_sched_barrier(0)
#define WAIT_LGKM0 do { asm volatile("s_waitcnt lgkmcnt(0)" ::: "memory"); FENCE_SCHED; } while (0)
#define WAIT_VMN(N) do { asm volatile("s_waitcnt vmcnt(" #N ")" ::: "memory"); FENCE_SCHED; } while (0)
// barrier with lgkm-only drain: DMA prefetches stay in flight across phases
#define BARRIER_LGKM do { \
  asm volatile("s_waitcnt lgkmcnt(0)" ::: "memory"); \
  __builtin_amdgcn_s_barrier(); FENCE_SCHED; } while (0)

// ---------------- prep: bf16-cast + transpose into chunk-swizzled K-tiles ----------------
// all tiles [N][32], 16B chunk cp holds source k-chunk cp^((r>>1)&3)
__global__ void prep_kernel(const float* __restrict__ w1, const float* __restrict__ w2,
                            const float* __restrict__ w3, u16* __restrict__ w1s,
                            u16* __restrict__ w2s, u16* __restrict__ w3s) {
  int i = blockIdx.x * 256 + threadIdx.x;
  if (i < 393216) {                       // 32 tiles [384][32]
    int t = i / 12288, p = i % 12288;
    int r = p >> 5, q = p & 31, cp = q >> 3, o = q & 7;
    int k = t * 32 + ((cp ^ ((r >> 1) & 3)) << 3) + o;
    w1s[i] = f2bf(w1[k * 384 + r]);
  } else if (i < 442368) {                // 12 tiles [128][32]
    int j = i - 393216;
    int t = j / 4096, p = j % 4096;
    int r = p >> 5, q = p & 31, cp = q >> 3, o = q & 7;
    int k = t * 32 + ((cp ^ ((r >> 1) & 3)) << 3) + o;
    w2s[j] = f2bf(w2[k * 128 + r]);
  } else if (i < 540672) {                // 8 tiles [384][32]
    int j = i - 442368;
    int t = j / 12288, p = j % 12288;
    int r = p >> 5, q = p & 31, cp = q >> 3, o = q & 7;
    int k = t * 32 + ((cp ^ ((r >> 1) & 3)) << 3) + o;
    w3s[j] = f2bf(w3[k * 384 + r]);
  }
}

// ---------------- fused forward ----------------
__global__ __launch_bounds__(BDIM, 4) void fused_kernel(
    const float* __restrict__ x,  const u16* __restrict__ w1s,
    const float* __restrict__ b1, const u16* __restrict__ w2s,
    const float* __restrict__ b2, const float* __restrict__ mkw,
    const float* __restrict__ mvw, const u16* __restrict__ w3s,
    const float* __restrict__ b3, const float* __restrict__ w4,
    const float* __restrict__ b4, float* __restrict__ out) {
  extern __shared__ char smem[];
  u16*   z1  = (u16*)(smem + Z1_OFF);
  u16*   fz  = (u16*)(smem + FZ_OFF);
  u16*   w3t = (u16*)(smem + W3T_OFF);
  u16*   wt0 = (u16*)(smem + WT0_OFF);
  u16*   wt1 = (u16*)(smem + WT1_OFF);
  float* b1s = (float*)(smem + B1S_OFF);
  float* b2s = (float*)(smem + B2S_OFF);
  float* b3s = (float*)(smem + B3S_OFF);
  float* w4s = (float*)(smem + W4S_OFF);
  u16*   mks = (u16*)(smem + MKS_OFF);
  float* rowpart = (float*)(smem + RP_OFF);

  const int tid  = threadIdx.x;
  const int lane = tid & 63;
  const int wid  = tid >> 6;          // 0..7: wave owns 48 w-cols (G1/G3), 16 (G2)
  const int l15  = lane & 15;
  const int g    = lane >> 4;         // 0..3
  const int sw8  = (g ^ ((l15 >> 1) & 3)) * 8;   // swizzled chunk (u16 offset)
  const int row0 = blockIdx.x * BM;
  const int wrow = wid * 48;
  const int wstrip = wid * 1536;      // 48-row strip in [384][32] (u16)

  // ---------- prologue ----------
  if (tid < 384) b1s[tid] = b1[tid];
  if (tid < 128) b2s[tid] = b2[tid];
  if (tid < 384) b3s[tid] = b3[tid];
  if (tid < 384) w4s[tid] = w4[tid];
  {
    int r = tid >> 4, cc = (tid & 15) * 8;
    const float4* p = (const float4*)(mkw + r * 128 + cc);
    *(u16x8*)(mks + r * 136 + cc) = cvt8(p[0], p[1]);
  }
  // W strips for kt=0 (->WT0) and kt=1 (->WT1)
  {
    const u16* ws = w1s + wstrip + lane * 8;
    gload16(ws, wt0 + wstrip); gload16(ws + 512, wt0 + wstrip + 512);
    gload16(ws + 1024, wt0 + wstrip + 1024);
    const u16* ws1 = ws + 12288;
    gload16(ws1, wt1 + wstrip); gload16(ws1 + 512, wt1 + wstrip + 512);
    gload16(ws1 + 1024, wt1 + wstrip + 1024);
  }
  FENCE_SCHED;
  // x: thread covers row=tid>>3, 4 k-cols (tid&7)*4, one float4 per tile
  const int xrow = tid >> 3, xq = tid & 7;
  const float* xp = x + (long)(row0 + xrow) * INDIM + xq * 4;
  const int xpub = xrow * 32 + (((xq >> 1) ^ ((xrow >> 1) & 3)) << 3) + (xq & 1) * 4;
  float4 xA = *(const float4*)xp, xB = *(const float4*)(xp + 32);
  // publish xt[0], xt[1] into pair A (implicit waits drain prologue loads; prologue-only)
  *(u16x4*)((u16*)(smem + XTA_OFF) + xpub)        = cvt4(xA);
  *(u16x4*)((u16*)(smem + XTA_OFF) + 2048 + xpub) = cvt4(xB);
  // stream x(2), x(3)
  xA = *(const float4*)(xp + 64); xB = *(const float4*)(xp + 96);
  BARRIER_LGKM;   // in-flight: [x:2] (W0/W1 drained by publish's implicit vmcnt)

  // =========== GEMM1: z1 = gelu(x@w1+b1) [64x384], K=1024, BK=32, 2 kt/phase ===========
  f32x4 acc[4][3];
  #pragma unroll
  for (int m = 0; m < 4; ++m)
    #pragma unroll
    for (int n = 0; n < 3; ++n) acc[m][n] = (f32x4){0.f, 0.f, 0.f, 0.f};

  for (int p = 0; p < 14; ++p) {
    const u16* xrb = (const u16*)(smem + ((p & 1) ? XTB_OFF : XTA_OFF));
    u16* xwb = (u16*)(smem + ((p & 1) ? XTA_OFF : XTB_OFF));
    // ---- kt = 2p (WT0) ----
    WAIT_VMN(5);                     // W(2p) landed; [W(2p+1):3, x:2] may fly
    {
      u16x8 af[4], bfr[3];
      #pragma unroll
      for (int m = 0; m < 4; ++m) af[m] = *(const u16x8*)(xrb + (m * 16 + l15) * 32 + sw8);
      #pragma unroll
      for (int n = 0; n < 3; ++n) bfr[n] = *(const u16x8*)(wt0 + (wrow + n * 16 + l15) * 32 + sw8);
      WAIT_LGKM0;                    // my WT0 strip reads done -> overwrite OK
      const u16* ws = w1s + (2 * p + 2) * 12288 + wstrip + lane * 8;
      gload16(ws, wt0 + wstrip); gload16(ws + 512, wt0 + wstrip + 512);
      gload16(ws + 1024, wt0 + wstrip + 1024);
      #pragma unroll
      for (int m = 0; m < 4; ++m)
        #pragma unroll
        for (int n = 0; n < 3; ++n) acc[m][n] = mfma16(bfr[n], af[m], acc[m][n]);
    }
    // ---- kt = 2p+1 (WT1) ----
    WAIT_VMN(5);                     // W(2p+1) landed; [x:2, W(2p+2):3] fly
    {
      u16x8 af[4], bfr[3];
      #pragma unroll
      for (int m = 0; m < 4; ++m) af[m] = *(const u16x8*)(xrb + 2048 + (m * 16 + l15) * 32 + sw8);
      #pragma unroll
      for (int n = 0; n < 3; ++n) bfr[n] = *(const u16x8*)(wt1 + (wrow + n * 16 + l15) * 32 + sw8);
      WAIT_LGKM0;
      const u16* ws = w1s + (2 * p + 3) * 12288 + wstrip + lane * 8;
      gload16(ws, wt1 + wstrip); gload16(ws + 512, wt1 + wstrip + 512);
      gload16(ws + 1024, wt1 + wstrip + 1024);
      #pragma unroll
      for (int m = 0; m < 4; ++m)
        #pragma unroll
        for (int n = 0; n < 3; ++n) acc[m][n] = mfma16(bfr[n], af[m], acc[m][n]);
    }
    // ---- publish xt(2p+2), xt(2p+3); implicit vmcnt(6) drains only the 2 x-loads ----
    *(u16x4*)(xwb + xpub)        = cvt4(xA);
    *(u16x4*)(xwb + 2048 + xpub) = cvt4(xB);
    xA = *(const float4*)(xp + (2 * p + 4) * 32);
    xB = *(const float4*)(xp + (2 * p + 5) * 32);
    BARRIER_LGKM;                    // steady in-flight: [W_e:3, W_o:3, x:2]
  }
  {   // ---- phase 14 (kt 28,29): DMA W30,W31; publish xt30,31; no x-load ----
    const u16* xrb = (const u16*)(smem + XTA_OFF);
    u16* xwb = (u16*)(smem + XTB_OFF);
    WAIT_VMN(5);
    {
      u16x8 af[4], bfr[3];
      #pragma unroll
      for (int m = 0; m < 4; ++m) af[m] = *(const u16x8*)(xrb + (m * 16 + l15) * 32 + sw8);
      #pragma unroll
      for (int n = 0; n < 3; ++n) bfr[n] = *(const u16x8*)(wt0 + (wrow + n * 16 + l15) * 32 + sw8);
      WAIT_LGKM0;
      const u16* ws = w1s + 30 * 12288 + wstrip + lane * 8;
      gload16(ws, wt0 + wstrip); gload16(ws + 512, wt0 + wstrip + 512);
      gload16(ws + 1024, wt0 + wstrip + 1024);
      #pragma unroll
      for (int m = 0; m < 4; ++m)
        #pragma unroll
        for (int n = 0; n < 3; ++n) acc[m][n] = mfma16(bfr[n], af[m], acc[m][n]);
    }
    WAIT_VMN(5);
    {
      u16x8 af[4], bfr[3];
      #pragma unroll
      for (int m = 0; m < 4; ++m) af[m] = *(const u16x8*)(xrb + 2048 + (m * 16 + l15) * 32 + sw8);
      #pragma unroll
      for (int n = 0; n < 3; ++n) bfr[n] = *(const u16x8*)(wt1 + (wrow + n * 16 + l15) * 32 + sw8);
      WAIT_LGKM0;
      const u16* ws = w1s + 31 * 12288 + wstrip + lane * 8;
      gload16(ws, wt1 + wstrip); gload16(ws + 512, wt1 + wstrip + 512);
      gload16(ws + 1024, wt1 + wstrip + 1024);
      #pragma unroll
      for (int m = 0; m < 4; ++m)
        #pragma unroll
        for (int n = 0; n < 3; ++n) acc[m][n] = mfma16(bfr[n], af[m], acc[m][n]);
    }
    *(u16x4*)(xwb + xpub)        = cvt4(xA);   // implicit vmcnt(6): drains x only
    *(u16x4*)(xwb + 2048 + xpub) = cvt4(xB);
    BARRIER_LGKM;                    // in-flight: [W30:3, W31:3]
  }
  {   // ---- phase 15 (kt 30,31): drain ----
    const u16* xrb = (const u16*)(smem + XTB_OFF);
    WAIT_VMN(3);
    {
      u16x8 af[4], bfr[3];
      #pragma unroll
      for (int m = 0; m < 4; ++m) af[m] = *(const u16x8*)(xrb + (m * 16 + l15) * 32 + sw8);
      #pragma unroll
      for (int n = 0; n < 3; ++n) bfr[n] = *(const u16x8*)(wt0 + (wrow + n * 16 + l15) * 32 + sw8);
      WAIT_LGKM0;
      #pragma unroll
      for (int m = 0; m < 4; ++m)
        #pragma unroll
        for (int n = 0; n < 3; ++n) acc[m][n] = mfma16(bfr[n], af[m], acc[m][n]);
    }
    WAIT_VMN(0);
    {
      u16x8 af[4], bfr[3];
      #pragma unroll
      for (int m = 0; m < 4; ++m) af[m] = *(const u16x8*)(xrb + 2048 + (m * 16 + l15) * 32 + sw8);
      #pragma unroll
      for (int n = 0; n < 3; ++n) bfr[n] = *(const u16x8*)(wt1 + (wrow + n * 16 + l15) * 32 + sw8);
      WAIT_LGKM0;
      #pragma unroll
      for (int m = 0; m < 4; ++m)
        #pragma unroll
        for (int n = 0; n < 3; ++n) acc[m][n] = mfma16(bfr[n], af[m], acc[m][n]);
    }
  }
  BARRIER_LGKM;                      // all staging reads done -> region reusable

  // G2 strips 0,1 DMA (wave-private, land under z1 epilogue)
  {
    const u16* s2 = w2s + wid * 512 + lane * 8;
    gload16(s2, (u16*)(smem + W2T0_OFF) + wid * 512);
    const u16* s2b = w2s + 4096 + wid * 512 + lane * 8;
    gload16(s2b, (u16*)(smem + W2T1_OFF) + wid * 512);
  }
  // z1 epilogue: b64 writes of 4 consecutive cols
  #pragma unroll
  for (int m = 0; m < 4; ++m) {
    #pragma unroll
    for (int n = 0; n < 3; ++n) {
      int col = wrow + n * 16 + g * 4;
      float4 bv = *(const float4*)(b1s + col);
      f32x4 a = acc[m][n];
      float4 gv = {gelu_fast(a[0] + bv.x), gelu_fast(a[1] + bv.y),
                   gelu_fast(a[2] + bv.z), gelu_fast(a[3] + bv.w)};
      *(u16x4*)(z1 + (m * 16 + l15) * 392 + col) = cvt4(gv);
    }
  }
  BARRIER_LGKM;                      // z1 visible

  // =========== GEMM2: z = gelu(z1@w2+b2) [64x128], K=384, BK=32, no barriers ===========
  f32x4 acc2[4];
  #pragma unroll
  for (int m = 0; m < 4; ++m) acc2[m] = (f32x4){0.f, 0.f, 0.f, 0.f};
  for (int kt = 0; kt < 12; ++kt) {
    if (kt < 10) { WAIT_VMN(1); } else { WAIT_VMN(0); }
    const u16* wb = (const u16*)(smem + ((kt & 1) ? W2T1_OFF : W2T0_OFF));
    u16x8 a2f[4];
    #pragma unroll
    for (int m = 0; m < 4; ++m)
      a2f[m] = *(const u16x8*)(z1 + (m * 16 + l15) * 392 + kt * 32 + g * 8);
    u16x8 b2f = *(const u16x8*)(wb + (wid * 16 + l15) * 32 + sw8);
    WAIT_LGKM0;
    if (kt < 10) {
      const u16* s2 = w2s + (kt + 2) * 4096 + wid * 512 + lane * 8;
      gload16(s2, (u16*)(smem + ((kt & 1) ? W2T1_OFF : W2T0_OFF)) + wid * 512);
    }
    #pragma unroll
    for (int m = 0; m < 4; ++m) acc2[m] = mfma16(b2f, a2f[m], acc2[m]);
  }
  BARRIER_LGKM;                      // z1/w2t dead -> fz & w3t regions usable

  // G3 strip(0) DMA early (covered by fz epilogue + logits + top2)
  {
    const u16* s3 = w3s + wid * 1536 + lane * 8;
    u16* d3 = w3t + wid * 1536;
    gload16(s3, d3); gload16(s3 + 512, d3 + 512); gload16(s3 + 1024, d3 + 1024);
  }
  // fz epilogue (z part)
  #pragma unroll
  for (int m = 0; m < 4; ++m) {
    int col = wid * 16 + g * 4;
    float4 bv = *(const float4*)(b2s + col);
    f32x4 a = acc2[m];
    float4 gv = {gelu_fast(a[0] + bv.x), gelu_fast(a[1] + bv.y),
                 gelu_fast(a[2] + bv.z), gelu_fast(a[3] + bv.w)};
    *(u16x4*)(fz + (m * 16 + l15) * 264 + col) = cvt4(gv);
  }
  BARRIER_LGKM;                      // fz(z) visible

  // =========== logits + in-register top-2 + mem blend (waves 0..3) ===========
  if (wid < 4) {
    const int wr = wid * 16 + l15;
    f32x4 accl[2] = {(f32x4){0,0,0,0}, (f32x4){0,0,0,0}};
    #pragma unroll
    for (int ks = 0; ks < 4; ++ks) {
      u16x8 afz = *(const u16x8*)(fz + wr * 264 + ks * 32 + g * 8);
      u16x8 k0  = *(const u16x8*)(mks + l15 * 136 + ks * 32 + g * 8);
      u16x8 k1  = *(const u16x8*)(mks + (16 + l15) * 136 + ks * 32 + g * 8);
      accl[0] = mfma16(k0, afz, accl[0]);
      accl[1] = mfma16(k1, afz, accl[1]);
    }
    float m1 = -3.4e38f, m2 = -3.4e38f; int i1 = -1, i2 = -1;
    #pragma unroll
    for (int n = 0; n < 2; ++n)
      #pragma unroll
      for (int j = 0; j < 4; ++j) {
        float v = accl[n][j]; int idx = n * 16 + g * 4 + j;
        if (v > m1) { m2 = m1; i2 = i1; m1 = v; i1 = idx; }
        else if (v > m2) { m2 = v; i2 = idx; }
      }
    #pragma unroll
    for (int d = 16; d <= 32; d <<= 1) {
      float om1 = __shfl_xor(m1, d); int oi1 = __shfl_xor(i1, d);
      float om2 = __shfl_xor(m2, d); int oi2 = __shfl_xor(i2, d);
      bool take = (om1 > m1) || (om1 == m1 && oi1 < i1);
      if (take) {
        float nm2; int ni2;
        if (m1 > om2 || (m1 == om2 && i1 < oi2)) { nm2 = m1; ni2 = i1; }
        else { nm2 = om2; ni2 = oi2; }
        m1 = om1; i1 = oi1; m2 = nm2; i2 = ni2;
      } else {
        if (om1 > m2 || (om1 == m2 && oi1 < i2)) { m2 = om1; i2 = oi1; }
      }
    }
    float a1 = __builtin_amdgcn_rcpf(
        1.0f + __builtin_amdgcn_exp2f((m2 - m1) * (1.44269504f / 0.7f)));
    float a2 = 1.0f - a1;
    const float* v1 = mvw + i1 * 128 + g * 32;
    const float* v2 = mvw + i2 * 128 + g * 32;
    #pragma unroll
    for (int c = 0; c < 4; ++c) {
      float4 A0 = *(const float4*)(v1 + c * 8), A1 = *(const float4*)(v1 + c * 8 + 4);
      float4 B0 = *(const float4*)(v2 + c * 8), B1 = *(const float4*)(v2 + c * 8 + 4);
      float4 r0 = {a1*A0.x + a2*B0.x, a1*A0.y + a2*B0.y, a1*A0.z + a2*B0.z, a1*A0.w + a2*B0.w};
      float4 r1 = {a1*A1.x + a2*B1.x, a1*A1.y + a2*B1.y, a1*A1.z + a2*B1.z, a1*A1.w + a2*B1.w};
      *(u16x8*)(fz + wr * 264 + 128 + g * 32 + c * 8) = cvt8(r0, r1);
    }
  }
  BARRIER_LGKM;                      // mem visible

  // =========== GEMM3: h = gelu(fused@w3+b3) [64x384], K=256, BK=32, no barriers ===========
  f32x4 acc3[4][3];
  #pragma unroll
  for (int m = 0; m < 4; ++m)
    #pragma unroll
    for (int n = 0; n < 3; ++n) acc3[m][n] = (f32x4){0.f, 0.f, 0.f, 0.f};
  for (int kt = 0; kt < 8; ++kt) {
    WAIT_VMN(0);                     // my strip(kt) landed
    u16x8 a3f[4], b3f[3];
    #pragma unroll
    for (int m = 0; m < 4; ++m)
      a3f[m] = *(const u16x8*)(fz + (m * 16 + l15) * 264 + kt * 32 + g * 8);
    #pragma unroll
    for (int n = 0; n < 3; ++n)
      b3f[n] = *(const u16x8*)(w3t + (wrow + n * 16 + l15) * 32 + sw8);
    WAIT_LGKM0;
    if (kt < 7) {
      const u16* s3 = w3s + (kt + 1) * 12288 + wid * 1536 + lane * 8;
      u16* d3 = w3t + wid * 1536;
      gload16(s3, d3); gload16(s3 + 512, d3 + 512); gload16(s3 + 1024, d3 + 1024);
    }
    #pragma unroll
    for (int m = 0; m < 4; ++m)
      #pragma unroll
      for (int n = 0; n < 3; ++n) acc3[m][n] = mfma16(b3f[n], a3f[m], acc3[m][n]);
  }

  // epilogue: per-row dot with w4; lane holds 4 consecutive cols -> 2-step shuffle reduce
  #pragma unroll
  for (int m = 0; m < 4; ++m) {
    float s = 0.f;
    #pragma unroll
    for (int n = 0; n < 3; ++n) {
      int col = wrow + n * 16 + g * 4;
      float4 bv = *(const float4*)(b3s + col);
      float4 wv = *(const float4*)(w4s + col);
      f32x4 a = acc3[m][n];
      s += gelu_fast(a[0] + bv.x) * wv.x + gelu_fast(a[1] + bv.y) * wv.y +
           gelu_fast(a[2] + bv.z) * wv.z + gelu_fast(a[3] + bv.w) * wv.w;
    }
    s += __shfl_xor(s, 16);
    s += __shfl_xor(s, 32);
    if (lane < 16) rowpart[(m * 16 + l15) * 8 + wid] = s;
  }
  BARRIER_LGKM;
  if (tid < BM) {
    const float4* rp = (const float4*)(rowpart + tid * 8);
    float4 p0 = rp[0], p1 = rp[1];
    float lg = b4[0] + p0.x + p0.y + p0.z + p0.w + p1.x + p1.y + p1.z + p1.w;
    out[row0 + tid] = __builtin_amdgcn_rcpf(1.0f + __builtin_amdgcn_exp2f(-lg * 1.44269504f));
  }
}

// ---------------- launch ----------------
extern "C" void kernel_launch(void* const* d_in, const int* in_sizes, int n_in,
                              void* d_out, int out_size, void* d_ws, size_t ws_size,
                              hipStream_t stream) {
  const float* x  = (const float*)d_in[0];
  const float* w1 = (const float*)d_in[1];
  const float* b1 = (const float*)d_in[2];
  const float* w2 = (const float*)d_in[3];
  const float* b2 = (const float*)d_in[4];
  const float* mk = (const float*)d_in[5];
  const float* mv = (const float*)d_in[6];
  const float* w3 = (const float*)d_in[7];
  const float* b3 = (const float*)d_in[8];
  const float* w4 = (const float*)d_in[9];
  const float* b4 = (const float*)d_in[10];

  u16* w1s = (u16*)d_ws;            // 393216 u16 (32 swizzled [384][32] tiles)
  u16* w2s = w1s + 393216;          // 49152 (12 [128][32] tiles)
  u16* w3s = w1s + 442368;          // 98304 (8 [384][32] tiles)

  prep_kernel<<<2112, 256, 0, stream>>>(w1, w2, w3, w1s, w2s, w3s);

  (void)hipFuncSetAttribute(reinterpret_cast<const void*>(fused_kernel),
                            hipFuncAttributeMaxDynamicSharedMemorySize, SMEM_BYTES);
  fused_kernel<<<NBLK, BDIM, SMEM_BYTES, stream>>>(x, w1s, b1, w2s, b2, mk, mv, w3s,
                                                   b3, w4, b4, (float*)d_out);
}